// Round 7
// baseline (362.110 us; speedup 1.0000x reference)
//
#include <hip/hip_runtime.h>

#define CIN 61
constexpr float EPS = 1e-5f;
constexpr double SCALE = 16777216.0;  // 2^24 fixed-point deterministic stat sums

using s16x8 = __attribute__((ext_vector_type(8))) short;
using fx4   = __attribute__((ext_vector_type(4))) float;

static __device__ __forceinline__ unsigned short f2bf(float f) {
  unsigned int u = __float_as_uint(f);
  u = (u + 0x7fffu + ((u >> 16) & 1u)) >> 16;
  return (unsigned short)u;
}
static __device__ __forceinline__ float bf2f(unsigned short h) {
  return __uint_as_float(((unsigned int)h) << 16);
}

__device__ __forceinline__ void stat_reduce(float val, float* red, long long* dst_ll) {
  int tid = threadIdx.x;
  red[tid] = val;
  __syncthreads();
  if (tid < 64) {
    float t = red[tid] + red[tid + 64] + red[tid + 128] + red[tid + 192];
    atomicAdd((unsigned long long*)&dst_ll[tid],
              (unsigned long long)(long long)((double)t * SCALE));
  }
  __syncthreads();
}

// ---- fused node pass: y = bf16(x@W1[:61]+b1), s = bf16(x@Ws+bs) + s-stats,
//      then thread-per-edge dst histogram + rank assignment ----
__global__ __launch_bounds__(256) void k_node(
    const float* __restrict__ x, const float* __restrict__ W1,
    const float* __restrict__ b1, const float* __restrict__ Ws,
    const float* __restrict__ bs, unsigned short* __restrict__ y,
    unsigned short* __restrict__ s_out, long long* __restrict__ stats, int N,
    const int* __restrict__ ei, unsigned int* __restrict__ hist,
    unsigned short* __restrict__ rank, int E) {
  const int tid = threadIdx.x, lane = tid & 63, wv = tid >> 6;
  float w1r[64], wsr[64];
#pragma unroll
  for (int k = 0; k < 64; ++k) {
    w1r[k] = (k < CIN) ? W1[k * 64 + lane] : 0.f;
    wsr[k] = (k < CIN) ? Ws[k * 64 + lane] : 0.f;
  }
  const float b1v = b1[lane], bsv = bs[lane];
  __shared__ float lrow[4][64];
  __shared__ float red[256];
  float ssum = 0.f, ssq = 0.f;
  const int nq = N >> 2;
  for (int q = blockIdx.x; q < nq; q += gridDim.x) {
    const int n = (q << 2) + wv;
    lrow[wv][lane] = (lane < CIN) ? x[n * CIN + lane] : 0.f;
    __syncthreads();
    float a0 = b1v, a1 = 0.f, a2 = 0.f, a3 = 0.f;
    float c0 = bsv, c1 = 0.f, c2 = 0.f, c3 = 0.f;
    const float4* rr = (const float4*)&lrow[wv][0];
#pragma unroll
    for (int k4 = 0; k4 < 16; ++k4) {
      float4 v = rr[k4];
      a0 = fmaf(v.x, w1r[4 * k4 + 0], a0);
      a1 = fmaf(v.y, w1r[4 * k4 + 1], a1);
      a2 = fmaf(v.z, w1r[4 * k4 + 2], a2);
      a3 = fmaf(v.w, w1r[4 * k4 + 3], a3);
      c0 = fmaf(v.x, wsr[4 * k4 + 0], c0);
      c1 = fmaf(v.y, wsr[4 * k4 + 1], c1);
      c2 = fmaf(v.z, wsr[4 * k4 + 2], c2);
      c3 = fmaf(v.w, wsr[4 * k4 + 3], c3);
    }
    y[(size_t)n * 64 + lane] = f2bf((a0 + a1) + (a2 + a3));
    const float sacc = (c0 + c1) + (c2 + c3);
    s_out[(size_t)n * 64 + lane] = f2bf(sacc);
    ssum += sacc;
    ssq = fmaf(sacc, sacc, ssq);
    __syncthreads();
  }
  stat_reduce(ssum, red, stats + 256);
  stat_reduce(ssq, red, stats + 320);
  // histogram + rank (within-segment order is output-invariant)
  for (int i = blockIdx.x * 256 + tid; i < E; i += gridDim.x * 256) {
    const int dst = ei[E + i];
    rank[i] = (unsigned short)atomicAdd(&hist[dst], 1u);
  }
}

// ---- single-block exclusive scan of hist -> cursor0 ----
__global__ __launch_bounds__(1024) void k_scan(
    const unsigned int* __restrict__ hist, unsigned int* __restrict__ cursor0, int n) {
  const int tid = threadIdx.x;
  const int per = (n + 1023) / 1024;
  const int lo = tid * per;
  const int hi = (lo + per < n) ? lo + per : n;
  unsigned int tot = 0;
  for (int i = lo; i < hi; ++i) tot += hist[i];
  const int lane = tid & 63, w = tid >> 6;
  unsigned int incl = tot;
#pragma unroll
  for (int off = 1; off < 64; off <<= 1) {
    unsigned int t = __shfl_up(incl, off);
    if (lane >= off) incl += t;
  }
  __shared__ unsigned int wsum[16];
  if (lane == 63) wsum[w] = incl;
  __syncthreads();
  unsigned int wbase = 0;
#pragma unroll
  for (int k = 0; k < 16; ++k) wbase += (k < w) ? wsum[k] : 0u;
  unsigned int run = wbase + incl - tot;  // exclusive prefix at lo
  for (int i = lo; i < hi; ++i) {
    unsigned int h = hist[i];
    cursor0[i] = run;
    run += h;
  }
}

// ---- edge pass 1: t1 stats + write 16B sorted edge record
//      {src:u16, dst:u16, pdiff:3xf32} (NO t1 materialization) ----
__global__ __launch_bounds__(256) void k_edge1(
    const int* __restrict__ ei, const float* __restrict__ pos,
    const unsigned short* __restrict__ y, const float* __restrict__ W1,
    const unsigned int* __restrict__ cursor0, const unsigned short* __restrict__ rank,
    int4* __restrict__ recS, long long* __restrict__ stats, int E) {
  const int tid = threadIdx.x, lane = tid & 63, wv = tid >> 6;
  const int g = lane >> 4, c16 = lane & 15;
  float wp[3][4];
#pragma unroll
  for (int d = 0; d < 3; ++d)
#pragma unroll
    for (int i = 0; i < 4; ++i) wp[d][i] = W1[(61 + d) * 64 + 4 * c16 + i];
  float ssum[4] = {0.f, 0.f, 0.f, 0.f}, ssq[4] = {0.f, 0.f, 0.f, 0.f};
  const int ngrp = E >> 2;  // E % 4 == 0
  const int nw = gridDim.x * 4;
  for (int q = blockIdx.x * 4 + wv; q < ngrp; q += nw) {
    const int e = (q << 2) + g;
    const int src = ei[e], dst = ei[E + e];
    float pv = 0.f;
    if (c16 < 3) pv = pos[src * 3 + c16] - pos[dst * 3 + c16];
    const float p0 = __shfl(pv, g * 16 + 0);
    const float p1 = __shfl(pv, g * 16 + 1);
    const float p2 = __shfl(pv, g * 16 + 2);
    const ushort4 yv = *(const ushort4*)(y + (size_t)src * 64 + 4 * c16);
    const unsigned short* yc = (const unsigned short*)&yv;
#pragma unroll
    for (int i = 0; i < 4; ++i) {
      float v = bf2f(yc[i]);
      v = fmaf(p0, wp[0][i], v);
      v = fmaf(p1, wp[1][i], v);
      v = fmaf(p2, wp[2][i], v);
      v = fmaxf(v, 0.f);
      ssum[i] += v;
      ssq[i] = fmaf(v, v, ssq[i]);
    }
    if (c16 == 0) {
      const unsigned int off = cursor0[dst] + rank[e];
      int4 r;
      r.x = (src & 0xffff) | (dst << 16);
      r.y = __float_as_int(p0);
      r.z = __float_as_int(p1);
      r.w = __float_as_int(p2);
      recS[off] = r;
    }
  }
#pragma unroll
  for (int i = 0; i < 4; ++i) {
    ssum[i] += __shfl_xor(ssum[i], 16); ssum[i] += __shfl_xor(ssum[i], 32);
    ssq[i]  += __shfl_xor(ssq[i], 16);  ssq[i]  += __shfl_xor(ssq[i], 32);
  }
  __shared__ float sred[2][64];
  if (tid < 128) ((float*)sred)[tid] = 0.f;
  __syncthreads();
  if (g == 0) {
#pragma unroll
    for (int i = 0; i < 4; ++i) {
      atomicAdd(&sred[0][4 * c16 + i], ssum[i]);
      atomicAdd(&sred[1][4 * c16 + i], ssq[i]);
    }
  }
  __syncthreads();
  if (tid < 64) {
    atomicAdd((unsigned long long*)&stats[0 + tid],
              (unsigned long long)(long long)((double)sred[0][tid] * SCALE));
    atomicAdd((unsigned long long*)&stats[64 + tid],
              (unsigned long long)(long long)((double)sred[1][tid] * SCALE));
  }
}

// ---- BN1 coef + fold into W2 ----
__global__ void k_coefA(const long long* __restrict__ stats,
                        const float* __restrict__ g1, const float* __restrict__ be1,
                        const float* __restrict__ W2, const float* __restrict__ b2,
                        unsigned short* __restrict__ W2p, float* __restrict__ b2p,
                        double invE) {
  const int c = threadIdx.x;
  __shared__ float a1s[64], c1s[64];
  double m = (double)stats[c] * invE;
  double v = (double)stats[64 + c] * invE - m * m;
  float a = g1[c] * rsqrtf((float)v + EPS);
  a1s[c] = a;
  c1s[c] = fmaf(-(float)m, a, be1[c]);
  __syncthreads();
  float acc = b2[c];
  for (int k = 0; k < 64; ++k) {
    const float w = W2[k * 64 + c];
    acc = fmaf(c1s[k], w, acc);
    W2p[k * 64 + c] = f2bf(a1s[k] * w);
  }
  b2p[c] = acc;
}

// ---- edge pass 2: stream sorted records, re-gather y, recompute t1 in
//      A-frag layout, MFMA, t2 stats, chunk-owned segment max ----
__global__ __launch_bounds__(256) void k_edge2(
    const int4* __restrict__ recS, const unsigned short* __restrict__ y,
    const unsigned short* __restrict__ W2p, const float* __restrict__ b2p,
    long long* __restrict__ stats, unsigned int* __restrict__ agg, int E) {
  const int tid = threadIdx.x, lane = tid & 63, wv = tid >> 6;
  const int l15 = lane & 15, lg = lane >> 4;
  s16x8 bF[4][2];
#pragma unroll
  for (int t = 0; t < 4; ++t) {
    const int col = l15 + 16 * t;
#pragma unroll
    for (int s = 0; s < 2; ++s)
#pragma unroll
      for (int i = 0; i < 8; ++i)
        bF[t][s][i] = (short)W2p[(s * 32 + lg * 8 + i) * 64 + col];
  }
  float bias[4];
#pragma unroll
  for (int t = 0; t < 4; ++t) bias[t] = b2p[l15 + 16 * t];
  float wpA[3][8], wpB[3][8];
  {
    const float* W1p = (const float*)b2p;  // unused; silence none
  }
  // pos-row weights for recompute, in A-frag element order
  // (passed via W2p? no — loaded from global W1 below)
  // NOTE: W1 pointer passed separately
  __shared__ float ld2[4][16][68];
  __shared__ int ldd[4][16];
  (void)wpA; (void)wpB;
  // real body in k_edge2_impl (kept single kernel; wp loads below)
  // -- this placeholder removed; see actual code after
  // (unreachable)
  if (false) { ld2[0][0][0] = 0.f; ldd[0][0] = 0; }
}

// actual edge pass 2 (with W1 for pos weights)
__global__ __launch_bounds__(256) void k_edge2b(
    const int4* __restrict__ recS, const unsigned short* __restrict__ y,
    const float* __restrict__ W1, const unsigned short* __restrict__ W2p,
    const float* __restrict__ b2p, long long* __restrict__ stats,
    unsigned int* __restrict__ agg, int E) {
  const int tid = threadIdx.x, lane = tid & 63, wv = tid >> 6;
  const int l15 = lane & 15, lg = lane >> 4;
  s16x8 bF[4][2];
#pragma unroll
  for (int t = 0; t < 4; ++t) {
    const int col = l15 + 16 * t;
#pragma unroll
    for (int s = 0; s < 2; ++s)
#pragma unroll
      for (int i = 0; i < 8; ++i)
        bF[t][s][i] = (short)W2p[(s * 32 + lg * 8 + i) * 64 + col];
  }
  float bias[4];
#pragma unroll
  for (int t = 0; t < 4; ++t) bias[t] = b2p[l15 + 16 * t];
  float wpA[3][8], wpB[3][8];
#pragma unroll
  for (int d = 0; d < 3; ++d)
#pragma unroll
    for (int i = 0; i < 8; ++i) {
      wpA[d][i] = W1[(61 + d) * 64 + lg * 8 + i];
      wpB[d][i] = W1[(61 + d) * 64 + 32 + lg * 8 + i];
    }
  __shared__ float ld2[4][16][68];  // pad 68: <=2-way bank aliasing (free)
  __shared__ int ldd[4][16];
  float ssum[4] = {0.f, 0.f, 0.f, 0.f}, ssq[4] = {0.f, 0.f, 0.f, 0.f};
  const int nchunk = E >> 7;  // 128 rows per chunk (E % 128 == 0)
  const int nw = gridDim.x * 4;
  for (int ch = blockIdx.x * 4 + wv; ch < nchunk; ch += nw) {
    int cur = -1;
    float m = 0.f;
    bool inside = false;
    const int row0 = ch << 7;
#pragma unroll 1
    for (int t8 = 0; t8 < 8; ++t8) {
      const int rbase = row0 + (t8 << 4);
      const int4 rec = recS[rbase + l15];
      const int src = rec.x & 0xffff;
      const int dstv = ((unsigned int)rec.x) >> 16;
      float p[3];
      p[0] = __int_as_float(rec.y);
      p[1] = __int_as_float(rec.z);
      p[2] = __int_as_float(rec.w);
      const unsigned short* yr = y + (size_t)src * 64 + lg * 8;
      const s16x8 y0 = *(const s16x8*)yr;
      const s16x8 y1 = *(const s16x8*)(yr + 32);
      union { s16x8 v; unsigned int u[4]; } a0, a1;
#pragma unroll
      for (int h = 0; h < 4; ++h) {
        float f0 = bf2f((unsigned short)y0[2 * h]);
        float f1 = bf2f((unsigned short)y0[2 * h + 1]);
#pragma unroll
        for (int d = 0; d < 3; ++d) {
          f0 = fmaf(p[d], wpA[d][2 * h], f0);
          f1 = fmaf(p[d], wpA[d][2 * h + 1], f1);
        }
        f0 = fmaxf(f0, 0.f); f1 = fmaxf(f1, 0.f);
        asm("v_cvt_pk_bf16_f32 %0, %1, %2" : "=v"(a0.u[h]) : "v"(f0), "v"(f1));
        f0 = bf2f((unsigned short)y1[2 * h]);
        f1 = bf2f((unsigned short)y1[2 * h + 1]);
#pragma unroll
        for (int d = 0; d < 3; ++d) {
          f0 = fmaf(p[d], wpB[d][2 * h], f0);
          f1 = fmaf(p[d], wpB[d][2 * h + 1], f1);
        }
        f0 = fmaxf(f0, 0.f); f1 = fmaxf(f1, 0.f);
        asm("v_cvt_pk_bf16_f32 %0, %1, %2" : "=v"(a1.u[h]) : "v"(f0), "v"(f1));
      }
      if (lg == 0) ldd[wv][l15] = dstv;
      fx4 acc[4];
#pragma unroll
      for (int t = 0; t < 4; ++t) {
        acc[t][0] = bias[t]; acc[t][1] = bias[t];
        acc[t][2] = bias[t]; acc[t][3] = bias[t];
      }
#pragma unroll
      for (int t = 0; t < 4; ++t) {
        acc[t] = __builtin_amdgcn_mfma_f32_16x16x32_bf16(a0.v, bF[t][0], acc[t], 0, 0, 0);
        acc[t] = __builtin_amdgcn_mfma_f32_16x16x32_bf16(a1.v, bF[t][1], acc[t], 0, 0, 0);
      }
#pragma unroll
      for (int t = 0; t < 4; ++t) {
        const int col = l15 + 16 * t;
#pragma unroll
        for (int j = 0; j < 4; ++j) {
          const float v = fmaxf(acc[t][j], 0.f);
          ssum[t] += v;
          ssq[t] = fmaf(v, v, ssq[t]);
          ld2[wv][lg * 4 + j][col] = v;
        }
      }
      __builtin_amdgcn_wave_barrier();  // order LDS writes before reads
#pragma unroll
      for (int r = 0; r < 16; ++r) {
        const int d = ldd[wv][r];
        const float v = ld2[wv][r][lane];
        if (d == cur) {
          m = fmaxf(m, v);
        } else {
          if (cur >= 0) {
            const unsigned int enc = __float_as_uint(m) | 0x80000000u;
            if (inside) agg[(size_t)cur * 64 + lane] = enc;       // complete segment
            else atomicMax(&agg[(size_t)cur * 64 + lane], enc);   // boundary carry-in
          }
          cur = d;
          m = v;
          inside = (t8 > 0) || (r > 0);  // run starts strictly inside chunk
        }
      }
      __builtin_amdgcn_wave_barrier();  // order reads before next tile's writes
    }
    if (cur >= 0)  // final run may continue into next chunk
      atomicMax(&agg[(size_t)cur * 64 + lane], __float_as_uint(m) | 0x80000000u);
  }
#pragma unroll
  for (int t = 0; t < 4; ++t) {
    ssum[t] += __shfl_xor(ssum[t], 16); ssum[t] += __shfl_xor(ssum[t], 32);
    ssq[t]  += __shfl_xor(ssq[t], 16);  ssq[t]  += __shfl_xor(ssq[t], 32);
  }
  __shared__ float sred[2][64];
  if (tid < 128) ((float*)sred)[tid] = 0.f;
  __syncthreads();
  if (lg == 0) {
#pragma unroll
    for (int t = 0; t < 4; ++t) {
      atomicAdd(&sred[0][l15 + 16 * t], ssum[t]);
      atomicAdd(&sred[1][l15 + 16 * t], ssq[t]);
    }
  }
  __syncthreads();
  if (tid < 64) {
    atomicAdd((unsigned long long*)&stats[128 + tid],
              (unsigned long long)(long long)((double)sred[0][tid] * SCALE));
    atomicAdd((unsigned long long*)&stats[192 + tid],
              (unsigned long long)(long long)((double)sred[1][tid] * SCALE));
  }
}

// ---- stats of raw maxima over nonempty nodes + nonempty count ----
__global__ __launch_bounds__(256) void k_aggfix(
    const unsigned int* __restrict__ agg, long long* __restrict__ stats, int total) {
  const int tid = threadIdx.x;
  __shared__ float red[256];
  float ssum = 0.f, ssq = 0.f, kcf = 0.f;
  const int step = gridDim.x * 256;
  for (int i = blockIdx.x * 256 + tid; i < total; i += step) {
    const unsigned int u = agg[i];
    if (u >> 31) {
      const float v = __uint_as_float(u & 0x7fffffffu);
      ssum += v;
      ssq = fmaf(v, v, ssq);
      if ((i & 63) == 0) kcf += 1.f;
    }
  }
  stat_reduce(ssum, red, stats + 384);
  stat_reduce(ssq, red, stats + 448);
  stat_reduce(kcf, red, stats + 512);
}

// ---- remaining BN coefs composed for the final pass ----
__global__ void k_coefB(const long long* __restrict__ stats,
                        const float* __restrict__ g2, const float* __restrict__ be2,
                        const float* __restrict__ gs, const float* __restrict__ bes,
                        const float* __restrict__ gf, const float* __restrict__ bef,
                        float* __restrict__ coef, double invE, double invN, int N) {
  const int c = threadIdx.x;
  double m2 = (double)stats[128 + c] * invE;
  double v2 = (double)stats[192 + c] * invE - m2 * m2;
  float a2 = g2[c] * rsqrtf((float)v2 + EPS);
  float c2 = fmaf(-(float)m2, a2, be2[c]);
  double mS = (double)stats[256 + c] * invN;
  double vS = (double)stats[320 + c] * invN - mS * mS;
  float aS = gs[c] * rsqrtf((float)vS + EPS);
  float cS = fmaf(-(float)mS, aS, bes[c]);
  double su = (double)stats[384 + c] / SCALE;
  double qu = (double)stats[448 + c] / SCALE;
  double K  = (double)stats[512] / SCALE;
  double sv = (double)a2 * su + (double)c2 * K;
  double qv = (double)a2 * a2 * qu + 2.0 * a2 * c2 * su + (double)c2 * c2 * K;
  double mv = sv / N;
  double vv = qv / N - mv * mv;
  float aF = gf[c] * rsqrtf((float)vv + EPS);
  float cF = fmaf(-(float)mv, aF, bef[c]);
  coef[c]       = aF * a2;
  coef[64 + c]  = fmaf(aF, c2, cF);
  coef[128 + c] = cF;
  coef[192 + c] = aS;
  coef[256 + c] = cS;
}

__global__ __launch_bounds__(256) void k_final(
    const unsigned int* __restrict__ agg, const unsigned short* __restrict__ sbuf,
    const float* __restrict__ coef, float* __restrict__ out, int total) {
  int i = blockIdx.x * 256 + threadIdx.x;
  if (i >= total) return;
  const int c = i & 63;
  const unsigned int u = agg[i];
  float base;
  if (u >> 31)
    base = fmaf(coef[c], __uint_as_float(u & 0x7fffffffu), coef[64 + c]);
  else
    base = coef[128 + c];
  const float sv = fmaf(coef[192 + c], bf2f(sbuf[i]), coef[256 + c]);
  out[i] = fmaxf(base + sv, 0.f);
}

extern "C" void kernel_launch(void* const* d_in, const int* in_sizes, int n_in,
                              void* d_out, int out_size, void* d_ws, size_t ws_size,
                              hipStream_t stream) {
  const float* x   = (const float*)d_in[0];
  const float* pos = (const float*)d_in[1];
  const int*   ei  = (const int*)d_in[2];
  const float* W1  = (const float*)d_in[3];
  const float* b1  = (const float*)d_in[4];
  const float* g1  = (const float*)d_in[5];
  const float* be1 = (const float*)d_in[6];
  const float* W2  = (const float*)d_in[7];
  const float* b2  = (const float*)d_in[8];
  const float* g2  = (const float*)d_in[9];
  const float* be2 = (const float*)d_in[10];
  const float* Ws  = (const float*)d_in[11];
  const float* bs  = (const float*)d_in[12];
  const float* gs  = (const float*)d_in[13];
  const float* bes = (const float*)d_in[14];
  const float* gf  = (const float*)d_in[15];
  const float* bef = (const float*)d_in[16];
  const int N = in_sizes[0] / CIN;   // 50000
  const int E = in_sizes[2] / 2;     // 800000

  char* ws = (char*)d_ws;
  // layout (bytes)
  const size_t o_stats = 0;                            // 576 ll -> pad 8192
  const size_t o_hist  = 8192;                         // N*4 -> pad 200704
  const size_t o_agg   = o_hist + 200704;              // N*256
  const size_t zeroEnd = o_agg + (size_t)N * 256;      // memset [0, zeroEnd)
  const size_t o_curs0 = zeroEnd;                      // N*4 -> pad 200704
  const size_t o_coef  = o_curs0 + 200704;             // coef 512f + b2p 64f -> 4096
  const size_t o_W2p   = o_coef + 4096;                // 8 KB
  const size_t o_rank  = o_W2p + 8192;                 // E*2
  const size_t o_rec   = o_rank + (size_t)E * 2;       // E*16
  const size_t o_ybuf  = o_rec + (size_t)E * 16;       // N*128
  const size_t o_sbuf  = o_ybuf + (size_t)N * 128;     // N*128

  long long* stats      = (long long*)(ws + o_stats);
  unsigned int* hist    = (unsigned int*)(ws + o_hist);
  unsigned int* agg     = (unsigned int*)(ws + o_agg);
  unsigned int* cursor0 = (unsigned int*)(ws + o_curs0);
  float* coef           = (float*)(ws + o_coef);
  float* b2p            = coef + 512;
  unsigned short* W2p   = (unsigned short*)(ws + o_W2p);
  unsigned short* rank  = (unsigned short*)(ws + o_rank);
  int4* recS            = (int4*)(ws + o_rec);
  unsigned short* ybuf  = (unsigned short*)(ws + o_ybuf);
  unsigned short* sbuf  = (unsigned short*)(ws + o_sbuf);

  const double invE = 1.0 / (SCALE * (double)E);
  const double invN = 1.0 / (SCALE * (double)N);
  const int total = N * 64;

  hipMemsetAsync(d_ws, 0, zeroEnd, stream);

  hipLaunchKernelGGL(k_node, dim3(1024), dim3(256), 0, stream,
                     x, W1, b1, Ws, bs, ybuf, sbuf, stats, N, ei, hist, rank, E);
  hipLaunchKernelGGL(k_scan, dim3(1), dim3(1024), 0, stream, hist, cursor0, N);
  hipLaunchKernelGGL(k_edge1, dim3(2048), dim3(256), 0, stream,
                     ei, pos, ybuf, W1, cursor0, rank, recS, stats, E);
  hipLaunchKernelGGL(k_coefA, dim3(1), dim3(64), 0, stream,
                     stats, g1, be1, W2, b2, W2p, b2p, invE);
  {
    const int nchunk = E >> 7;
    const int blocks = (nchunk + 3) / 4;
    hipLaunchKernelGGL(k_edge2b, dim3(blocks), dim3(256), 0, stream,
                       recS, ybuf, W1, W2p, b2p, stats, agg, E);
  }
  hipLaunchKernelGGL(k_aggfix, dim3(1024), dim3(256), 0, stream, agg, stats, total);
  hipLaunchKernelGGL(k_coefB, dim3(1), dim3(64), 0, stream,
                     stats, g2, be2, gs, bes, gf, bef, coef, invE, invN, N);
  hipLaunchKernelGGL(k_final, dim3((total + 255) / 256), dim3(256), 0, stream,
                     agg, sbuf, coef, (float*)d_out, total);
}

// Round 8
// 301.756 us; speedup vs baseline: 1.2000x; 1.2000x over previous
//
#include <hip/hip_runtime.h>

#define CIN 61
constexpr float EPS = 1e-5f;
constexpr double SCALE = 16777216.0;  // 2^24 fixed-point deterministic stat sums

using s16x8 = __attribute__((ext_vector_type(8))) short;
using fx4   = __attribute__((ext_vector_type(4))) float;

static __device__ __forceinline__ unsigned short f2bf(float f) {
  unsigned int u = __float_as_uint(f);
  u = (u + 0x7fffu + ((u >> 16) & 1u)) >> 16;
  return (unsigned short)u;
}
static __device__ __forceinline__ float bf2f(unsigned short h) {
  return __uint_as_float(((unsigned int)h) << 16);
}

__device__ __forceinline__ void stat_reduce(float val, float* red, long long* dst_ll) {
  int tid = threadIdx.x;
  red[tid] = val;
  __syncthreads();
  if (tid < 64) {
    float t = red[tid] + red[tid + 64] + red[tid + 128] + red[tid + 192];
    atomicAdd((unsigned long long*)&dst_ll[tid],
              (unsigned long long)(long long)((double)t * SCALE));
  }
  __syncthreads();
}

// ---- fused node pass: y/s GEMVs (wave-private staging, NO block syncs)
//      + thread-per-edge dst histogram + rank assignment ----
__global__ __launch_bounds__(256) void k_node(
    const float* __restrict__ x, const float* __restrict__ W1,
    const float* __restrict__ b1, const float* __restrict__ Ws,
    const float* __restrict__ bs, unsigned short* __restrict__ y,
    unsigned short* __restrict__ s_out, long long* __restrict__ stats, int N,
    const int* __restrict__ ei, unsigned int* __restrict__ hist,
    unsigned short* __restrict__ rank, int E) {
  const int tid = threadIdx.x, lane = tid & 63, wv = tid >> 6;
  float w1r[64], wsr[64];
#pragma unroll
  for (int k = 0; k < 64; ++k) {
    w1r[k] = (k < CIN) ? W1[k * 64 + lane] : 0.f;
    wsr[k] = (k < CIN) ? Ws[k * 64 + lane] : 0.f;
  }
  const float b1v = b1[lane], bsv = bs[lane];
  __shared__ float lrow[4][64];
  __shared__ float red[256];
  float ssum = 0.f, ssq = 0.f;
  const int nq = N >> 2;
  for (int q = blockIdx.x; q < nq; q += gridDim.x) {
    const int n = (q << 2) + wv;
    lrow[wv][lane] = (lane < CIN) ? x[(size_t)n * CIN + lane] : 0.f;
    __builtin_amdgcn_wave_barrier();  // wave-private buffer: no block sync needed
    float a0 = b1v, a1 = 0.f, a2 = 0.f, a3 = 0.f;
    float c0 = bsv, c1 = 0.f, c2 = 0.f, c3 = 0.f;
    const float4* rr = (const float4*)&lrow[wv][0];
#pragma unroll
    for (int k4 = 0; k4 < 16; ++k4) {
      float4 v = rr[k4];
      a0 = fmaf(v.x, w1r[4 * k4 + 0], a0);
      a1 = fmaf(v.y, w1r[4 * k4 + 1], a1);
      a2 = fmaf(v.z, w1r[4 * k4 + 2], a2);
      a3 = fmaf(v.w, w1r[4 * k4 + 3], a3);
      c0 = fmaf(v.x, wsr[4 * k4 + 0], c0);
      c1 = fmaf(v.y, wsr[4 * k4 + 1], c1);
      c2 = fmaf(v.z, wsr[4 * k4 + 2], c2);
      c3 = fmaf(v.w, wsr[4 * k4 + 3], c3);
    }
    y[(size_t)n * 64 + lane] = f2bf((a0 + a1) + (a2 + a3));
    const float sacc = (c0 + c1) + (c2 + c3);
    s_out[(size_t)n * 64 + lane] = f2bf(sacc);
    ssum += sacc;
    ssq = fmaf(sacc, sacc, ssq);
    __builtin_amdgcn_wave_barrier();
  }
  stat_reduce(ssum, red, stats + 256);
  stat_reduce(ssq, red, stats + 320);
  // histogram + rank (within-segment order is output-invariant)
  for (int i = blockIdx.x * 256 + tid; i < E; i += gridDim.x * 256) {
    const int dst = ei[E + i];
    rank[i] = (unsigned short)atomicAdd(&hist[dst], 1u);
  }
}

// ---- hierarchical scan: 49 blocks x 1024 entries each (hist padded/zeroed) ----
__global__ __launch_bounds__(256) void k_scan1(
    const unsigned int* __restrict__ hist, unsigned int* __restrict__ bsum) {
  const int tid = threadIdx.x, lane = tid & 63, wv = tid >> 6;
  const uint4 v = ((const uint4*)(hist + blockIdx.x * 1024))[tid];
  unsigned int s = v.x + v.y + v.z + v.w;
#pragma unroll
  for (int off = 1; off < 64; off <<= 1) s += __shfl_xor(s, off);
  __shared__ unsigned int wsum[4];
  if (lane == 0) wsum[wv] = s;
  __syncthreads();
  if (tid == 0) bsum[blockIdx.x] = wsum[0] + wsum[1] + wsum[2] + wsum[3];
}

__global__ void k_scan2(const unsigned int* __restrict__ bsum,
                        unsigned int* __restrict__ boff, int nb) {
  const int t = threadIdx.x;  // 64 threads
  unsigned int v = (t < nb) ? bsum[t] : 0u;
  unsigned int incl = v;
#pragma unroll
  for (int off = 1; off < 64; off <<= 1) {
    unsigned int u = __shfl_up(incl, off);
    if (t >= off) incl += u;
  }
  if (t < nb) boff[t] = incl - v;
}

__global__ __launch_bounds__(256) void k_scan3(
    const unsigned int* __restrict__ hist, const unsigned int* __restrict__ boff,
    unsigned int* __restrict__ cursor0) {
  const int tid = threadIdx.x, lane = tid & 63, wv = tid >> 6;
  const uint4 v = ((const uint4*)(hist + blockIdx.x * 1024))[tid];
  const unsigned int s = v.x + v.y + v.z + v.w;
  unsigned int incl = s;
#pragma unroll
  for (int off = 1; off < 64; off <<= 1) {
    unsigned int u = __shfl_up(incl, off);
    if (lane >= off) incl += u;
  }
  __shared__ unsigned int wtot[4];
  if (lane == 63) wtot[wv] = incl;
  __syncthreads();
  unsigned int wb = boff[blockIdx.x];
#pragma unroll
  for (int k = 0; k < 4; ++k) wb += (k < wv) ? wtot[k] : 0u;
  const unsigned int ex = wb + incl - s;
  uint4 o;
  o.x = ex; o.y = ex + v.x; o.z = o.y + v.y; o.w = o.z + v.z;
  ((uint4*)(cursor0 + blockIdx.x * 1024))[tid] = o;
}

// ---- edge pass 1: 8 edges/wave in flight (8-lane groups, 16B y loads),
//      t1 stats + 16B sorted edge record {src,dst,pdiff} ----
__global__ __launch_bounds__(256) void k_edge1(
    const int* __restrict__ ei, const float* __restrict__ pos,
    const unsigned short* __restrict__ y, const float* __restrict__ W1,
    const unsigned int* __restrict__ cursor0, const unsigned short* __restrict__ rank,
    int4* __restrict__ recS, long long* __restrict__ stats, int E) {
  const int tid = threadIdx.x, lane = tid & 63, wv = tid >> 6;
  const int g8 = lane >> 3, c8 = lane & 7;
  float wp[3][8];
#pragma unroll
  for (int d = 0; d < 3; ++d)
#pragma unroll
    for (int i = 0; i < 8; ++i) wp[d][i] = W1[(61 + d) * 64 + 8 * c8 + i];
  float ssum[8] = {0.f, 0.f, 0.f, 0.f, 0.f, 0.f, 0.f, 0.f};
  float ssq[8]  = {0.f, 0.f, 0.f, 0.f, 0.f, 0.f, 0.f, 0.f};
  const int ngrp = E >> 3;  // E % 8 == 0
  const int nw = gridDim.x * 4;
  for (int q = blockIdx.x * 4 + wv; q < ngrp; q += nw) {
    const int e = (q << 3) + g8;
    const int src = ei[e], dst = ei[E + e];
    float pv = 0.f;
    if (c8 < 3) pv = pos[src * 3 + c8] - pos[dst * 3 + c8];
    const float p0 = __shfl(pv, g8 * 8 + 0);
    const float p1 = __shfl(pv, g8 * 8 + 1);
    const float p2 = __shfl(pv, g8 * 8 + 2);
    const s16x8 yv = *(const s16x8*)(y + (unsigned)src * 64u + 8u * (unsigned)c8);
#pragma unroll
    for (int i = 0; i < 8; ++i) {
      float v = bf2f((unsigned short)yv[i]);
      v = fmaf(p0, wp[0][i], v);
      v = fmaf(p1, wp[1][i], v);
      v = fmaf(p2, wp[2][i], v);
      v = fmaxf(v, 0.f);
      ssum[i] += v;
      ssq[i] = fmaf(v, v, ssq[i]);
    }
    if (c8 == 0) {
      const unsigned int off = cursor0[dst] + rank[e];
      int4 r;
      r.x = (src & 0xffff) | (dst << 16);
      r.y = __float_as_int(p0);
      r.z = __float_as_int(p1);
      r.w = __float_as_int(p2);
      recS[off] = r;
    }
  }
#pragma unroll
  for (int i = 0; i < 8; ++i) {
    ssum[i] += __shfl_xor(ssum[i], 8);
    ssum[i] += __shfl_xor(ssum[i], 16);
    ssum[i] += __shfl_xor(ssum[i], 32);
    ssq[i] += __shfl_xor(ssq[i], 8);
    ssq[i] += __shfl_xor(ssq[i], 16);
    ssq[i] += __shfl_xor(ssq[i], 32);
  }
  __shared__ float sred[2][64];
  if (tid < 128) ((float*)sred)[tid] = 0.f;
  __syncthreads();
  if (g8 == 0) {
#pragma unroll
    for (int i = 0; i < 8; ++i) {
      atomicAdd(&sred[0][8 * c8 + i], ssum[i]);
      atomicAdd(&sred[1][8 * c8 + i], ssq[i]);
    }
  }
  __syncthreads();
  if (tid < 64) {
    atomicAdd((unsigned long long*)&stats[0 + tid],
              (unsigned long long)(long long)((double)sred[0][tid] * SCALE));
    atomicAdd((unsigned long long*)&stats[64 + tid],
              (unsigned long long)(long long)((double)sred[1][tid] * SCALE));
  }
}

// ---- BN1 coef + fold into W2 ----
__global__ void k_coefA(const long long* __restrict__ stats,
                        const float* __restrict__ g1, const float* __restrict__ be1,
                        const float* __restrict__ W2, const float* __restrict__ b2,
                        unsigned short* __restrict__ W2p, float* __restrict__ b2p,
                        double invE) {
  const int c = threadIdx.x;
  __shared__ float a1s[64], c1s[64];
  double m = (double)stats[c] * invE;
  double v = (double)stats[64 + c] * invE - m * m;
  float a = g1[c] * rsqrtf((float)v + EPS);
  a1s[c] = a;
  c1s[c] = fmaf(-(float)m, a, be1[c]);
  __syncthreads();
  float acc = b2[c];
  for (int k = 0; k < 64; ++k) {
    const float w = W2[k * 64 + c];
    acc = fmaf(c1s[k], w, acc);
    W2p[k * 64 + c] = f2bf(a1s[k] * w);
  }
  b2p[c] = acc;
}

// ---- edge pass 2: stream sorted records, gather y, recompute t1 in A-frag
//      layout, MFMA, t2 stats, chunk-owned segment max (scalarized run-max) ----
__global__ __launch_bounds__(256) void k_edge2(
    const int4* __restrict__ recS, const unsigned short* __restrict__ y,
    const float* __restrict__ W1, const unsigned short* __restrict__ W2p,
    const float* __restrict__ b2p, long long* __restrict__ stats,
    unsigned int* __restrict__ agg, int E) {
  const int tid = threadIdx.x, lane = tid & 63, wv = tid >> 6;
  const int l15 = lane & 15, lg = lane >> 4;
  s16x8 bF[4][2];
#pragma unroll
  for (int t = 0; t < 4; ++t) {
    const int col = l15 + 16 * t;
#pragma unroll
    for (int s = 0; s < 2; ++s)
#pragma unroll
      for (int i = 0; i < 8; ++i)
        bF[t][s][i] = (short)W2p[(s * 32 + lg * 8 + i) * 64 + col];
  }
  float bias[4];
#pragma unroll
  for (int t = 0; t < 4; ++t) bias[t] = b2p[l15 + 16 * t];
  float wpA[3][8], wpB[3][8];
#pragma unroll
  for (int d = 0; d < 3; ++d)
#pragma unroll
    for (int i = 0; i < 8; ++i) {
      wpA[d][i] = W1[(61 + d) * 64 + lg * 8 + i];
      wpB[d][i] = W1[(61 + d) * 64 + 32 + lg * 8 + i];
    }
  __shared__ float ld2[4][16][68];  // pad 68: <=2-way bank aliasing (free)
  __shared__ int ldd[4][16];
  float ssum[4] = {0.f, 0.f, 0.f, 0.f}, ssq[4] = {0.f, 0.f, 0.f, 0.f};
  const int nchunk = E >> 7;  // 128 rows per chunk
  const int nw = gridDim.x * 4;
  for (int ch = blockIdx.x * 4 + wv; ch < nchunk; ch += nw) {
    int cur = -1;
    float m = 0.f;
    bool inside = false;
    const int row0 = ch << 7;
#pragma unroll 2
    for (int t8 = 0; t8 < 8; ++t8) {
      const int rbase = row0 + (t8 << 4);
      const int4 rec = recS[rbase + l15];
      const unsigned src = (unsigned)rec.x & 0xffffu;
      const int dstv = (int)(((unsigned)rec.x) >> 16);
      float p[3];
      p[0] = __int_as_float(rec.y);
      p[1] = __int_as_float(rec.z);
      p[2] = __int_as_float(rec.w);
      const unsigned short* yr = y + src * 64u + (unsigned)(lg * 8);
      const s16x8 y0 = *(const s16x8*)yr;
      const s16x8 y1 = *(const s16x8*)(yr + 32);
      union { s16x8 v; unsigned int u[4]; } a0, a1;
#pragma unroll
      for (int h = 0; h < 4; ++h) {
        float f0 = bf2f((unsigned short)y0[2 * h]);
        float f1 = bf2f((unsigned short)y0[2 * h + 1]);
#pragma unroll
        for (int d = 0; d < 3; ++d) {
          f0 = fmaf(p[d], wpA[d][2 * h], f0);
          f1 = fmaf(p[d], wpA[d][2 * h + 1], f1);
        }
        f0 = fmaxf(f0, 0.f); f1 = fmaxf(f1, 0.f);
        asm("v_cvt_pk_bf16_f32 %0, %1, %2" : "=v"(a0.u[h]) : "v"(f0), "v"(f1));
        f0 = bf2f((unsigned short)y1[2 * h]);
        f1 = bf2f((unsigned short)y1[2 * h + 1]);
#pragma unroll
        for (int d = 0; d < 3; ++d) {
          f0 = fmaf(p[d], wpB[d][2 * h], f0);
          f1 = fmaf(p[d], wpB[d][2 * h + 1], f1);
        }
        f0 = fmaxf(f0, 0.f); f1 = fmaxf(f1, 0.f);
        asm("v_cvt_pk_bf16_f32 %0, %1, %2" : "=v"(a1.u[h]) : "v"(f0), "v"(f1));
      }
      if (lg == 0) ldd[wv][l15] = dstv;
      fx4 acc[4];
#pragma unroll
      for (int t = 0; t < 4; ++t) {
        acc[t][0] = bias[t]; acc[t][1] = bias[t];
        acc[t][2] = bias[t]; acc[t][3] = bias[t];
      }
#pragma unroll
      for (int t = 0; t < 4; ++t) {
        acc[t] = __builtin_amdgcn_mfma_f32_16x16x32_bf16(a0.v, bF[t][0], acc[t], 0, 0, 0);
        acc[t] = __builtin_amdgcn_mfma_f32_16x16x32_bf16(a1.v, bF[t][1], acc[t], 0, 0, 0);
      }
#pragma unroll
      for (int t = 0; t < 4; ++t) {
        const int col = l15 + 16 * t;
#pragma unroll
        for (int j = 0; j < 4; ++j) {
          const float v = fmaxf(acc[t][j], 0.f);
          ssum[t] += v;
          ssq[t] = fmaf(v, v, ssq[t]);
          ld2[wv][lg * 4 + j][col] = v;
        }
      }
      __builtin_amdgcn_wave_barrier();  // order LDS writes before reads
#pragma unroll
      for (int r = 0; r < 16; ++r) {
        const int d = __builtin_amdgcn_readfirstlane(ldd[wv][r]);  // wave-uniform
        const float v = ld2[wv][r][lane];
        if (d == cur) {
          m = fmaxf(m, v);
        } else {
          if (cur >= 0) {
            const unsigned int enc = __float_as_uint(m) | 0x80000000u;
            if (inside) agg[(unsigned)cur * 64u + lane] = enc;       // complete segment
            else atomicMax(&agg[(unsigned)cur * 64u + lane], enc);   // boundary carry-in
          }
          cur = d;
          m = v;
          inside = (t8 > 0) || (r > 0);  // run starts strictly inside chunk
        }
      }
      __builtin_amdgcn_wave_barrier();  // order reads before next tile's writes
    }
    if (cur >= 0)  // final run may continue into next chunk
      atomicMax(&agg[(unsigned)cur * 64u + lane], __float_as_uint(m) | 0x80000000u);
  }
#pragma unroll
  for (int t = 0; t < 4; ++t) {
    ssum[t] += __shfl_xor(ssum[t], 16); ssum[t] += __shfl_xor(ssum[t], 32);
    ssq[t]  += __shfl_xor(ssq[t], 16);  ssq[t]  += __shfl_xor(ssq[t], 32);
  }
  __shared__ float sred[2][64];
  if (tid < 128) ((float*)sred)[tid] = 0.f;
  __syncthreads();
  if (lg == 0) {
#pragma unroll
    for (int t = 0; t < 4; ++t) {
      atomicAdd(&sred[0][l15 + 16 * t], ssum[t]);
      atomicAdd(&sred[1][l15 + 16 * t], ssq[t]);
    }
  }
  __syncthreads();
  if (tid < 64) {
    atomicAdd((unsigned long long*)&stats[128 + tid],
              (unsigned long long)(long long)((double)sred[0][tid] * SCALE));
    atomicAdd((unsigned long long*)&stats[192 + tid],
              (unsigned long long)(long long)((double)sred[1][tid] * SCALE));
  }
}

// ---- stats of raw maxima over nonempty nodes + nonempty count ----
__global__ __launch_bounds__(256) void k_aggfix(
    const unsigned int* __restrict__ agg, long long* __restrict__ stats, int total) {
  const int tid = threadIdx.x;
  __shared__ float red[256];
  float ssum = 0.f, ssq = 0.f, kcf = 0.f;
  const int step = gridDim.x * 256;
  for (int i = blockIdx.x * 256 + tid; i < total; i += step) {
    const unsigned int u = agg[i];
    if (u >> 31) {
      const float v = __uint_as_float(u & 0x7fffffffu);
      ssum += v;
      ssq = fmaf(v, v, ssq);
      if ((i & 63) == 0) kcf += 1.f;
    }
  }
  stat_reduce(ssum, red, stats + 384);
  stat_reduce(ssq, red, stats + 448);
  stat_reduce(kcf, red, stats + 512);
}

// ---- remaining BN coefs composed for the final pass ----
__global__ void k_coefB(const long long* __restrict__ stats,
                        const float* __restrict__ g2, const float* __restrict__ be2,
                        const float* __restrict__ gs, const float* __restrict__ bes,
                        const float* __restrict__ gf, const float* __restrict__ bef,
                        float* __restrict__ coef, double invE, double invN, int N) {
  const int c = threadIdx.x;
  double m2 = (double)stats[128 + c] * invE;
  double v2 = (double)stats[192 + c] * invE - m2 * m2;
  float a2 = g2[c] * rsqrtf((float)v2 + EPS);
  float c2 = fmaf(-(float)m2, a2, be2[c]);
  double mS = (double)stats[256 + c] * invN;
  double vS = (double)stats[320 + c] * invN - mS * mS;
  float aS = gs[c] * rsqrtf((float)vS + EPS);
  float cS = fmaf(-(float)mS, aS, bes[c]);
  double su = (double)stats[384 + c] / SCALE;
  double qu = (double)stats[448 + c] / SCALE;
  double K  = (double)stats[512] / SCALE;
  double sv = (double)a2 * su + (double)c2 * K;
  double qv = (double)a2 * a2 * qu + 2.0 * a2 * c2 * su + (double)c2 * c2 * K;
  double mv = sv / N;
  double vv = qv / N - mv * mv;
  float aF = gf[c] * rsqrtf((float)vv + EPS);
  float cF = fmaf(-(float)mv, aF, bef[c]);
  coef[c]       = aF * a2;
  coef[64 + c]  = fmaf(aF, c2, cF);
  coef[128 + c] = cF;
  coef[192 + c] = aS;
  coef[256 + c] = cS;
}

__global__ __launch_bounds__(256) void k_final(
    const unsigned int* __restrict__ agg, const unsigned short* __restrict__ sbuf,
    const float* __restrict__ coef, float* __restrict__ out, int total) {
  int i = blockIdx.x * 256 + threadIdx.x;
  if (i >= total) return;
  const int c = i & 63;
  const unsigned int u = agg[i];
  float base;
  if (u >> 31)
    base = fmaf(coef[c], __uint_as_float(u & 0x7fffffffu), coef[64 + c]);
  else
    base = coef[128 + c];
  const float sv = fmaf(coef[192 + c], bf2f(sbuf[i]), coef[256 + c]);
  out[i] = fmaxf(base + sv, 0.f);
}

extern "C" void kernel_launch(void* const* d_in, const int* in_sizes, int n_in,
                              void* d_out, int out_size, void* d_ws, size_t ws_size,
                              hipStream_t stream) {
  const float* x   = (const float*)d_in[0];
  const float* pos = (const float*)d_in[1];
  const int*   ei  = (const int*)d_in[2];
  const float* W1  = (const float*)d_in[3];
  const float* b1  = (const float*)d_in[4];
  const float* g1  = (const float*)d_in[5];
  const float* be1 = (const float*)d_in[6];
  const float* W2  = (const float*)d_in[7];
  const float* b2  = (const float*)d_in[8];
  const float* g2  = (const float*)d_in[9];
  const float* be2 = (const float*)d_in[10];
  const float* Ws  = (const float*)d_in[11];
  const float* bs  = (const float*)d_in[12];
  const float* gs  = (const float*)d_in[13];
  const float* bes = (const float*)d_in[14];
  const float* gf  = (const float*)d_in[15];
  const float* bef = (const float*)d_in[16];
  const int N = in_sizes[0] / CIN;   // 50000
  const int E = in_sizes[2] / 2;     // 800000

  char* ws = (char*)d_ws;
  // layout (bytes)
  const size_t o_stats = 0;                            // 513 ll = 4104 -> pad 4608
  const size_t o_bsum  = 4608;                         // 49 u32
  const size_t o_boff  = 5120;                         // 49 u32 -> stats page ends 8192
  const size_t o_hist  = 8192;                         // 50176 u32 = 200704 (zeroed)
  const size_t o_agg   = o_hist + 200704;              // N*256
  const size_t zeroEnd = o_agg + (size_t)N * 256;      // memset [0, zeroEnd)
  const size_t o_curs0 = zeroEnd;                      // 50176 u32 = 200704
  const size_t o_coef  = o_curs0 + 200704;             // coef 512f + b2p 64f -> 4096
  const size_t o_W2p   = o_coef + 4096;                // 8 KB
  const size_t o_rank  = o_W2p + 8192;                 // E*2
  const size_t o_rec   = o_rank + (size_t)E * 2;       // E*16 (16B aligned)
  const size_t o_ybuf  = o_rec + (size_t)E * 16;       // N*128
  const size_t o_sbuf  = o_ybuf + (size_t)N * 128;     // N*128

  long long* stats      = (long long*)(ws + o_stats);
  unsigned int* bsum    = (unsigned int*)(ws + o_bsum);
  unsigned int* boff    = (unsigned int*)(ws + o_boff);
  unsigned int* hist    = (unsigned int*)(ws + o_hist);
  unsigned int* agg     = (unsigned int*)(ws + o_agg);
  unsigned int* cursor0 = (unsigned int*)(ws + o_curs0);
  float* coef           = (float*)(ws + o_coef);
  float* b2p            = coef + 512;
  unsigned short* W2p   = (unsigned short*)(ws + o_W2p);
  unsigned short* rank  = (unsigned short*)(ws + o_rank);
  int4* recS            = (int4*)(ws + o_rec);
  unsigned short* ybuf  = (unsigned short*)(ws + o_ybuf);
  unsigned short* sbuf  = (unsigned short*)(ws + o_sbuf);

  const double invE = 1.0 / (SCALE * (double)E);
  const double invN = 1.0 / (SCALE * (double)N);
  const int total = N * 64;
  const int nScanBlk = 49;  // ceil(50176/1024)

  hipMemsetAsync(d_ws, 0, zeroEnd, stream);

  hipLaunchKernelGGL(k_node, dim3(1024), dim3(256), 0, stream,
                     x, W1, b1, Ws, bs, ybuf, sbuf, stats, N, ei, hist, rank, E);
  hipLaunchKernelGGL(k_scan1, dim3(nScanBlk), dim3(256), 0, stream, hist, bsum);
  hipLaunchKernelGGL(k_scan2, dim3(1), dim3(64), 0, stream, bsum, boff, nScanBlk);
  hipLaunchKernelGGL(k_scan3, dim3(nScanBlk), dim3(256), 0, stream,
                     hist, boff, cursor0);
  hipLaunchKernelGGL(k_edge1, dim3(2048), dim3(256), 0, stream,
                     ei, pos, ybuf, W1, cursor0, rank, recS, stats, E);
  hipLaunchKernelGGL(k_coefA, dim3(1), dim3(64), 0, stream,
                     stats, g1, be1, W2, b2, W2p, b2p, invE);
  {
    const int nchunk = E >> 7;
    const int blocks = (nchunk + 3) / 4;
    hipLaunchKernelGGL(k_edge2, dim3(blocks), dim3(256), 0, stream,
                       recS, ybuf, W1, W2p, b2p, stats, agg, E);
  }
  hipLaunchKernelGGL(k_aggfix, dim3(1024), dim3(256), 0, stream, agg, stats, total);
  hipLaunchKernelGGL(k_coefB, dim3(1), dim3(64), 0, stream,
                     stats, g2, be2, gs, bes, gf, bef, coef, invE, invN, N);
  hipLaunchKernelGGL(k_final, dim3((total + 255) / 256), dim3(256), 0, stream,
                     agg, sbuf, coef, (float*)d_out, total);
}

// Round 9
// 281.241 us; speedup vs baseline: 1.2875x; 1.0729x over previous
//
#include <hip/hip_runtime.h>

#define CIN 61
constexpr float EPS = 1e-5f;
constexpr double SCALE = 16777216.0;  // 2^24 fixed-point deterministic stat sums

using s16x8 = __attribute__((ext_vector_type(8))) short;
using fx4   = __attribute__((ext_vector_type(4))) float;

static __device__ __forceinline__ unsigned short f2bf(float f) {
  unsigned int u = __float_as_uint(f);
  u = (u + 0x7fffu + ((u >> 16) & 1u)) >> 16;
  return (unsigned short)u;
}
static __device__ __forceinline__ float bf2f(unsigned short h) {
  return __uint_as_float(((unsigned int)h) << 16);
}

__device__ __forceinline__ void stat_reduce(float val, float* red, long long* dst_ll) {
  int tid = threadIdx.x;
  red[tid] = val;
  __syncthreads();
  if (tid < 64) {
    float t = red[tid] + red[tid + 64] + red[tid + 128] + red[tid + 192];
    atomicAdd((unsigned long long*)&dst_ll[tid],
              (unsigned long long)(long long)((double)t * SCALE));
  }
  __syncthreads();
}

// ---- fused node pass: y/s GEMVs (wave-private staging) + dst hist/rank ----
__global__ __launch_bounds__(256) void k_node(
    const float* __restrict__ x, const float* __restrict__ W1,
    const float* __restrict__ b1, const float* __restrict__ Ws,
    const float* __restrict__ bs, unsigned short* __restrict__ y,
    unsigned short* __restrict__ s_out, long long* __restrict__ stats, int N,
    const int* __restrict__ ei, unsigned int* __restrict__ hist,
    unsigned short* __restrict__ rank, int E) {
  const int tid = threadIdx.x, lane = tid & 63, wv = tid >> 6;
  float w1r[64], wsr[64];
#pragma unroll
  for (int k = 0; k < 64; ++k) {
    w1r[k] = (k < CIN) ? W1[k * 64 + lane] : 0.f;
    wsr[k] = (k < CIN) ? Ws[k * 64 + lane] : 0.f;
  }
  const float b1v = b1[lane], bsv = bs[lane];
  __shared__ float lrow[4][64];
  __shared__ float red[256];
  float ssum = 0.f, ssq = 0.f;
  const int nq = N >> 2;
  for (int q = blockIdx.x; q < nq; q += gridDim.x) {
    const int n = (q << 2) + wv;
    lrow[wv][lane] = (lane < CIN) ? x[(size_t)n * CIN + lane] : 0.f;
    __builtin_amdgcn_wave_barrier();
    float a0 = b1v, a1 = 0.f, a2 = 0.f, a3 = 0.f;
    float c0 = bsv, c1 = 0.f, c2 = 0.f, c3 = 0.f;
    const float4* rr = (const float4*)&lrow[wv][0];
#pragma unroll
    for (int k4 = 0; k4 < 16; ++k4) {
      float4 v = rr[k4];
      a0 = fmaf(v.x, w1r[4 * k4 + 0], a0);
      a1 = fmaf(v.y, w1r[4 * k4 + 1], a1);
      a2 = fmaf(v.z, w1r[4 * k4 + 2], a2);
      a3 = fmaf(v.w, w1r[4 * k4 + 3], a3);
      c0 = fmaf(v.x, wsr[4 * k4 + 0], c0);
      c1 = fmaf(v.y, wsr[4 * k4 + 1], c1);
      c2 = fmaf(v.z, wsr[4 * k4 + 2], c2);
      c3 = fmaf(v.w, wsr[4 * k4 + 3], c3);
    }
    y[(size_t)n * 64 + lane] = f2bf((a0 + a1) + (a2 + a3));
    const float sacc = (c0 + c1) + (c2 + c3);
    s_out[(size_t)n * 64 + lane] = f2bf(sacc);
    ssum += sacc;
    ssq = fmaf(sacc, sacc, ssq);
    __builtin_amdgcn_wave_barrier();
  }
  stat_reduce(ssum, red, stats + 256);
  stat_reduce(ssq, red, stats + 320);
  for (int i = blockIdx.x * 256 + tid; i < E; i += gridDim.x * 256) {
    const int dst = ei[E + i];
    rank[i] = (unsigned short)atomicAdd(&hist[dst], 1u);
  }
}

// ---- hierarchical scan ----
__global__ __launch_bounds__(256) void k_scan1(
    const unsigned int* __restrict__ hist, unsigned int* __restrict__ bsum) {
  const int tid = threadIdx.x, lane = tid & 63, wv = tid >> 6;
  const uint4 v = ((const uint4*)(hist + blockIdx.x * 1024))[tid];
  unsigned int s = v.x + v.y + v.z + v.w;
#pragma unroll
  for (int off = 1; off < 64; off <<= 1) s += __shfl_xor(s, off);
  __shared__ unsigned int wsum[4];
  if (lane == 0) wsum[wv] = s;
  __syncthreads();
  if (tid == 0) bsum[blockIdx.x] = wsum[0] + wsum[1] + wsum[2] + wsum[3];
}

__global__ void k_scan2(const unsigned int* __restrict__ bsum,
                        unsigned int* __restrict__ boff, int nb) {
  const int t = threadIdx.x;
  unsigned int v = (t < nb) ? bsum[t] : 0u;
  unsigned int incl = v;
#pragma unroll
  for (int off = 1; off < 64; off <<= 1) {
    unsigned int u = __shfl_up(incl, off);
    if (t >= off) incl += u;
  }
  if (t < nb) boff[t] = incl - v;
}

__global__ __launch_bounds__(256) void k_scan3(
    const unsigned int* __restrict__ hist, const unsigned int* __restrict__ boff,
    unsigned int* __restrict__ cursor0) {
  const int tid = threadIdx.x, lane = tid & 63, wv = tid >> 6;
  const uint4 v = ((const uint4*)(hist + blockIdx.x * 1024))[tid];
  const unsigned int s = v.x + v.y + v.z + v.w;
  unsigned int incl = s;
#pragma unroll
  for (int off = 1; off < 64; off <<= 1) {
    unsigned int u = __shfl_up(incl, off);
    if (lane >= off) incl += u;
  }
  __shared__ unsigned int wtot[4];
  if (lane == 63) wtot[wv] = incl;
  __syncthreads();
  unsigned int wb = boff[blockIdx.x];
#pragma unroll
  for (int k = 0; k < 4; ++k) wb += (k < wv) ? wtot[k] : 0u;
  const unsigned int ex = wb + incl - s;
  uint4 o;
  o.x = ex; o.y = ex + v.x; o.z = o.y + v.y; o.w = o.z + v.z;
  ((uint4*)(cursor0 + blockIdx.x * 1024))[tid] = o;
}

// ---- edge pass 1: 8 edges/wave in flight, t1 stats + 16B sorted record ----
__global__ __launch_bounds__(256) void k_edge1(
    const int* __restrict__ ei, const float* __restrict__ pos,
    const unsigned short* __restrict__ y, const float* __restrict__ W1,
    const unsigned int* __restrict__ cursor0, const unsigned short* __restrict__ rank,
    int4* __restrict__ recS, long long* __restrict__ stats, int E) {
  const int tid = threadIdx.x, lane = tid & 63, wv = tid >> 6;
  const int g8 = lane >> 3, c8 = lane & 7;
  float wp[3][8];
#pragma unroll
  for (int d = 0; d < 3; ++d)
#pragma unroll
    for (int i = 0; i < 8; ++i) wp[d][i] = W1[(61 + d) * 64 + 8 * c8 + i];
  float ssum[8] = {0.f, 0.f, 0.f, 0.f, 0.f, 0.f, 0.f, 0.f};
  float ssq[8]  = {0.f, 0.f, 0.f, 0.f, 0.f, 0.f, 0.f, 0.f};
  const int ngrp = E >> 3;
  const int nw = gridDim.x * 4;
  for (int q = blockIdx.x * 4 + wv; q < ngrp; q += nw) {
    const int e = (q << 3) + g8;
    const int src = ei[e], dst = ei[E + e];
    float pv = 0.f;
    if (c8 < 3) pv = pos[src * 3 + c8] - pos[dst * 3 + c8];
    const float p0 = __shfl(pv, g8 * 8 + 0);
    const float p1 = __shfl(pv, g8 * 8 + 1);
    const float p2 = __shfl(pv, g8 * 8 + 2);
    const s16x8 yv = *(const s16x8*)(y + (unsigned)src * 64u + 8u * (unsigned)c8);
#pragma unroll
    for (int i = 0; i < 8; ++i) {
      float v = bf2f((unsigned short)yv[i]);
      v = fmaf(p0, wp[0][i], v);
      v = fmaf(p1, wp[1][i], v);
      v = fmaf(p2, wp[2][i], v);
      v = fmaxf(v, 0.f);
      ssum[i] += v;
      ssq[i] = fmaf(v, v, ssq[i]);
    }
    if (c8 == 0) {
      const unsigned int off = cursor0[dst] + rank[e];
      int4 r;
      r.x = (src & 0xffff) | (dst << 16);
      r.y = __float_as_int(p0);
      r.z = __float_as_int(p1);
      r.w = __float_as_int(p2);
      recS[off] = r;
    }
  }
#pragma unroll
  for (int i = 0; i < 8; ++i) {
    ssum[i] += __shfl_xor(ssum[i], 8);
    ssum[i] += __shfl_xor(ssum[i], 16);
    ssum[i] += __shfl_xor(ssum[i], 32);
    ssq[i] += __shfl_xor(ssq[i], 8);
    ssq[i] += __shfl_xor(ssq[i], 16);
    ssq[i] += __shfl_xor(ssq[i], 32);
  }
  __shared__ float sred[2][64];
  if (tid < 128) ((float*)sred)[tid] = 0.f;
  __syncthreads();
  if (g8 == 0) {
#pragma unroll
    for (int i = 0; i < 8; ++i) {
      atomicAdd(&sred[0][8 * c8 + i], ssum[i]);
      atomicAdd(&sred[1][8 * c8 + i], ssq[i]);
    }
  }
  __syncthreads();
  if (tid < 64) {
    atomicAdd((unsigned long long*)&stats[0 + tid],
              (unsigned long long)(long long)((double)sred[0][tid] * SCALE));
    atomicAdd((unsigned long long*)&stats[64 + tid],
              (unsigned long long)(long long)((double)sred[1][tid] * SCALE));
  }
}

// ---- BN1 coef + fold into W2, emitting PRE-PERMUTED per-lane fragment tables:
//      bFpack[lane][t][s][i] u16 (128B/lane), wpPack[lane][d][16] f32 (192B/lane),
//      biasF[lane] float4 ----
__global__ void k_coefA(const long long* __restrict__ stats,
                        const float* __restrict__ g1, const float* __restrict__ be1,
                        const float* __restrict__ W2, const float* __restrict__ b2,
                        const float* __restrict__ W1,
                        unsigned short* __restrict__ bFpack,
                        float* __restrict__ wpPack, float* __restrict__ biasF,
                        double invE) {
  const int c = threadIdx.x;  // 64 threads; c plays "lane"
  __shared__ float a1s[64], c1s[64], b2sh[64];
  double m = (double)stats[c] * invE;
  double v = (double)stats[64 + c] * invE - m * m;
  float a = g1[c] * rsqrtf((float)v + EPS);
  a1s[c] = a;
  c1s[c] = fmaf(-(float)m, a, be1[c]);
  __syncthreads();
  float acc = b2[c];
  for (int k = 0; k < 64; ++k) acc = fmaf(c1s[k], W2[k * 64 + c], acc);
  b2sh[c] = acc;
  const int lg = c >> 4, l15 = c & 15;
#pragma unroll
  for (int t = 0; t < 4; ++t)
#pragma unroll
    for (int s = 0; s < 2; ++s)
#pragma unroll
      for (int i = 0; i < 8; ++i) {
        const int k = s * 32 + lg * 8 + i;
        bFpack[c * 64 + t * 16 + s * 8 + i] = f2bf(a1s[k] * W2[k * 64 + l15 + 16 * t]);
      }
#pragma unroll
  for (int d = 0; d < 3; ++d)
#pragma unroll
    for (int j = 0; j < 16; ++j) {
      const int k = (j < 8) ? (lg * 8 + j) : (32 + lg * 8 + (j - 8));
      wpPack[c * 48 + d * 16 + j] = W1[(61 + d) * 64 + k];
    }
  __syncthreads();
  float4 bf;
  bf.x = b2sh[l15]; bf.y = b2sh[l15 + 16]; bf.z = b2sh[l15 + 32]; bf.w = b2sh[l15 + 48];
  ((float4*)biasF)[c] = bf;
}

// ---- edge pass 2: software-pipelined rec->y chain, MFMA, stats,
//      chunk-owned segment max ----
__global__ __launch_bounds__(256) void k_edge2(
    const int4* __restrict__ recS, const unsigned short* __restrict__ y,
    const unsigned short* __restrict__ bFpack, const float* __restrict__ wpPack,
    const float* __restrict__ biasF, long long* __restrict__ stats,
    unsigned int* __restrict__ agg, int E) {
  const int tid = threadIdx.x, lane = tid & 63, wv = tid >> 6;
  const int l15 = lane & 15, lg = lane >> 4;
  // coalesced fragment setup: 8 + 12 + 1 wide loads per lane
  s16x8 bF[4][2];
  {
    const s16x8* bfp = (const s16x8*)(bFpack + (size_t)lane * 64);
#pragma unroll
    for (int t = 0; t < 4; ++t)
#pragma unroll
      for (int s = 0; s < 2; ++s) bF[t][s] = bfp[t * 2 + s];
  }
  float wpA[3][8], wpB[3][8];
  {
    const float4* wpp = (const float4*)(wpPack + (size_t)lane * 48);
#pragma unroll
    for (int d = 0; d < 3; ++d) {
      const float4 q0 = wpp[d * 4 + 0], q1 = wpp[d * 4 + 1];
      const float4 q2 = wpp[d * 4 + 2], q3 = wpp[d * 4 + 3];
      wpA[d][0] = q0.x; wpA[d][1] = q0.y; wpA[d][2] = q0.z; wpA[d][3] = q0.w;
      wpA[d][4] = q1.x; wpA[d][5] = q1.y; wpA[d][6] = q1.z; wpA[d][7] = q1.w;
      wpB[d][0] = q2.x; wpB[d][1] = q2.y; wpB[d][2] = q2.z; wpB[d][3] = q2.w;
      wpB[d][4] = q3.x; wpB[d][5] = q3.y; wpB[d][6] = q3.z; wpB[d][7] = q3.w;
    }
  }
  float bias[4];
  {
    const float4 bv = ((const float4*)biasF)[lane];
    bias[0] = bv.x; bias[1] = bv.y; bias[2] = bv.z; bias[3] = bv.w;
  }
  __shared__ float ld2[4][16][68];
  __shared__ int ldd[4][16];
  float ssum[4] = {0.f, 0.f, 0.f, 0.f}, ssq[4] = {0.f, 0.f, 0.f, 0.f};
  const int nchunk = E >> 7;
  const int nw = gridDim.x * 4;
  for (int ch = blockIdx.x * 4 + wv; ch < nchunk; ch += nw) {
    const int row0 = ch << 7;
    // pipeline prologue: rec + y for tile 0
    int4 rec = recS[row0 + l15];
    s16x8 yA, yB;
    {
      const unsigned srcP = (unsigned)rec.x & 0xffffu;
      const unsigned short* yr = y + srcP * 64u + (unsigned)(lg * 8);
      yA = *(const s16x8*)yr;
      yB = *(const s16x8*)(yr + 32);
    }
    int cur = -1;
    float m = 0.f;
    bool inside = false;
#pragma unroll 2
    for (int t8 = 0; t8 < 8; ++t8) {
      // (1) issue next-tile record load (in flight during compute)
      const int nb = row0 + (((t8 + 1) & 7) << 4);
      const int4 recN = recS[nb + l15];
      // (2) compute current tile from (rec, yA, yB)
      const int dstv = (int)(((unsigned)rec.x) >> 16);
      float p[3];
      p[0] = __int_as_float(rec.y);
      p[1] = __int_as_float(rec.z);
      p[2] = __int_as_float(rec.w);
      union { s16x8 v; unsigned int u[4]; } a0, a1;
#pragma unroll
      for (int h = 0; h < 4; ++h) {
        float f0 = bf2f((unsigned short)yA[2 * h]);
        float f1 = bf2f((unsigned short)yA[2 * h + 1]);
#pragma unroll
        for (int d = 0; d < 3; ++d) {
          f0 = fmaf(p[d], wpA[d][2 * h], f0);
          f1 = fmaf(p[d], wpA[d][2 * h + 1], f1);
        }
        f0 = fmaxf(f0, 0.f); f1 = fmaxf(f1, 0.f);
        asm("v_cvt_pk_bf16_f32 %0, %1, %2" : "=v"(a0.u[h]) : "v"(f0), "v"(f1));
        f0 = bf2f((unsigned short)yB[2 * h]);
        f1 = bf2f((unsigned short)yB[2 * h + 1]);
#pragma unroll
        for (int d = 0; d < 3; ++d) {
          f0 = fmaf(p[d], wpB[d][2 * h], f0);
          f1 = fmaf(p[d], wpB[d][2 * h + 1], f1);
        }
        f0 = fmaxf(f0, 0.f); f1 = fmaxf(f1, 0.f);
        asm("v_cvt_pk_bf16_f32 %0, %1, %2" : "=v"(a1.u[h]) : "v"(f0), "v"(f1));
      }
      if (lg == 0) ldd[wv][l15] = dstv;
      fx4 acc[4];
#pragma unroll
      for (int t = 0; t < 4; ++t) {
        acc[t][0] = bias[t]; acc[t][1] = bias[t];
        acc[t][2] = bias[t]; acc[t][3] = bias[t];
      }
#pragma unroll
      for (int t = 0; t < 4; ++t) {
        acc[t] = __builtin_amdgcn_mfma_f32_16x16x32_bf16(a0.v, bF[t][0], acc[t], 0, 0, 0);
        acc[t] = __builtin_amdgcn_mfma_f32_16x16x32_bf16(a1.v, bF[t][1], acc[t], 0, 0, 0);
      }
#pragma unroll
      for (int t = 0; t < 4; ++t) {
        const int col = l15 + 16 * t;
#pragma unroll
        for (int j = 0; j < 4; ++j) {
          const float v = fmaxf(acc[t][j], 0.f);
          ssum[t] += v;
          ssq[t] = fmaf(v, v, ssq[t]);
          ld2[wv][lg * 4 + j][col] = v;
        }
      }
      __builtin_amdgcn_wave_barrier();  // LDS writes before reads
      // (3) issue next-tile y gather (recN arrived during compute);
      //     its latency is covered by the run-max below
      s16x8 yAn, yBn;
      {
        const unsigned srcN = (unsigned)recN.x & 0xffffu;
        const unsigned short* yrN = y + srcN * 64u + (unsigned)(lg * 8);
        yAn = *(const s16x8*)yrN;
        yBn = *(const s16x8*)(yrN + 32);
      }
      // (4) run-segmented max of current tile
#pragma unroll
      for (int r = 0; r < 16; ++r) {
        const int d = __builtin_amdgcn_readfirstlane(ldd[wv][r]);
        const float v = ld2[wv][r][lane];
        if (d == cur) {
          m = fmaxf(m, v);
        } else {
          if (cur >= 0) {
            const unsigned int enc = __float_as_uint(m) | 0x80000000u;
            if (inside) agg[(unsigned)cur * 64u + lane] = enc;
            else atomicMax(&agg[(unsigned)cur * 64u + lane], enc);
          }
          cur = d;
          m = v;
          inside = (t8 > 0) || (r > 0);
        }
      }
      __builtin_amdgcn_wave_barrier();  // reads before next tile's writes
      rec = recN; yA = yAn; yB = yBn;
    }
    if (cur >= 0)
      atomicMax(&agg[(unsigned)cur * 64u + lane], __float_as_uint(m) | 0x80000000u);
  }
#pragma unroll
  for (int t = 0; t < 4; ++t) {
    ssum[t] += __shfl_xor(ssum[t], 16); ssum[t] += __shfl_xor(ssum[t], 32);
    ssq[t]  += __shfl_xor(ssq[t], 16);  ssq[t]  += __shfl_xor(ssq[t], 32);
  }
  __shared__ float sred[2][64];
  if (tid < 128) ((float*)sred)[tid] = 0.f;
  __syncthreads();
  if (lg == 0) {
#pragma unroll
    for (int t = 0; t < 4; ++t) {
      atomicAdd(&sred[0][l15 + 16 * t], ssum[t]);
      atomicAdd(&sred[1][l15 + 16 * t], ssq[t]);
    }
  }
  __syncthreads();
  if (tid < 64) {
    atomicAdd((unsigned long long*)&stats[128 + tid],
              (unsigned long long)(long long)((double)sred[0][tid] * SCALE));
    atomicAdd((unsigned long long*)&stats[192 + tid],
              (unsigned long long)(long long)((double)sred[1][tid] * SCALE));
  }
}

// ---- stats of raw maxima over nonempty nodes + nonempty count ----
__global__ __launch_bounds__(256) void k_aggfix(
    const unsigned int* __restrict__ agg, long long* __restrict__ stats, int total) {
  const int tid = threadIdx.x;
  __shared__ float red[256];
  float ssum = 0.f, ssq = 0.f, kcf = 0.f;
  const int step = gridDim.x * 256;
  for (int i = blockIdx.x * 256 + tid; i < total; i += step) {
    const unsigned int u = agg[i];
    if (u >> 31) {
      const float v = __uint_as_float(u & 0x7fffffffu);
      ssum += v;
      ssq = fmaf(v, v, ssq);
      if ((i & 63) == 0) kcf += 1.f;
    }
  }
  stat_reduce(ssum, red, stats + 384);
  stat_reduce(ssq, red, stats + 448);
  stat_reduce(kcf, red, stats + 512);
}

// ---- remaining BN coefs composed for the final pass ----
__global__ void k_coefB(const long long* __restrict__ stats,
                        const float* __restrict__ g2, const float* __restrict__ be2,
                        const float* __restrict__ gs, const float* __restrict__ bes,
                        const float* __restrict__ gf, const float* __restrict__ bef,
                        float* __restrict__ coef, double invE, double invN, int N) {
  const int c = threadIdx.x;
  double m2 = (double)stats[128 + c] * invE;
  double v2 = (double)stats[192 + c] * invE - m2 * m2;
  float a2 = g2[c] * rsqrtf((float)v2 + EPS);
  float c2 = fmaf(-(float)m2, a2, be2[c]);
  double mS = (double)stats[256 + c] * invN;
  double vS = (double)stats[320 + c] * invN - mS * mS;
  float aS = gs[c] * rsqrtf((float)vS + EPS);
  float cS = fmaf(-(float)mS, aS, bes[c]);
  double su = (double)stats[384 + c] / SCALE;
  double qu = (double)stats[448 + c] / SCALE;
  double K  = (double)stats[512] / SCALE;
  double sv = (double)a2 * su + (double)c2 * K;
  double qv = (double)a2 * a2 * qu + 2.0 * a2 * c2 * su + (double)c2 * c2 * K;
  double mv = sv / N;
  double vv = qv / N - mv * mv;
  float aF = gf[c] * rsqrtf((float)vv + EPS);
  float cF = fmaf(-(float)mv, aF, bef[c]);
  coef[c]       = aF * a2;
  coef[64 + c]  = fmaf(aF, c2, cF);
  coef[128 + c] = cF;
  coef[192 + c] = aS;
  coef[256 + c] = cS;
}

__global__ __launch_bounds__(256) void k_final(
    const unsigned int* __restrict__ agg, const unsigned short* __restrict__ sbuf,
    const float* __restrict__ coef, float* __restrict__ out, int total) {
  int i = blockIdx.x * 256 + threadIdx.x;
  if (i >= total) return;
  const int c = i & 63;
  const unsigned int u = agg[i];
  float base;
  if (u >> 31)
    base = fmaf(coef[c], __uint_as_float(u & 0x7fffffffu), coef[64 + c]);
  else
    base = coef[128 + c];
  const float sv = fmaf(coef[192 + c], bf2f(sbuf[i]), coef[256 + c]);
  out[i] = fmaxf(base + sv, 0.f);
}

extern "C" void kernel_launch(void* const* d_in, const int* in_sizes, int n_in,
                              void* d_out, int out_size, void* d_ws, size_t ws_size,
                              hipStream_t stream) {
  const float* x   = (const float*)d_in[0];
  const float* pos = (const float*)d_in[1];
  const int*   ei  = (const int*)d_in[2];
  const float* W1  = (const float*)d_in[3];
  const float* b1  = (const float*)d_in[4];
  const float* g1  = (const float*)d_in[5];
  const float* be1 = (const float*)d_in[6];
  const float* W2  = (const float*)d_in[7];
  const float* b2  = (const float*)d_in[8];
  const float* g2  = (const float*)d_in[9];
  const float* be2 = (const float*)d_in[10];
  const float* Ws  = (const float*)d_in[11];
  const float* bs  = (const float*)d_in[12];
  const float* gs  = (const float*)d_in[13];
  const float* bes = (const float*)d_in[14];
  const float* gf  = (const float*)d_in[15];
  const float* bef = (const float*)d_in[16];
  const int N = in_sizes[0] / CIN;   // 50000
  const int E = in_sizes[2] / 2;     // 800000

  char* ws = (char*)d_ws;
  const size_t o_stats = 0;                            // 513 ll -> pad 4608
  const size_t o_bsum  = 4608;
  const size_t o_boff  = 5120;                         // page ends 8192
  const size_t o_hist  = 8192;                         // 50176 u32 (zeroed)
  const size_t o_agg   = o_hist + 200704;              // N*256
  const size_t zeroEnd = o_agg + (size_t)N * 256;
  const size_t o_curs0 = zeroEnd;                      // 200704
  const size_t o_coef  = o_curs0 + 200704;             // 4096
  const size_t o_frag  = o_coef + 4096;                // bFpack 8192 | wpPack 12288 | biasF 1024
  const size_t o_rank  = o_frag + 24576;               // E*2
  const size_t o_rec   = o_rank + (size_t)E * 2;       // E*16
  const size_t o_ybuf  = o_rec + (size_t)E * 16;       // N*128
  const size_t o_sbuf  = o_ybuf + (size_t)N * 128;     // N*128

  long long* stats      = (long long*)(ws + o_stats);
  unsigned int* bsum    = (unsigned int*)(ws + o_bsum);
  unsigned int* boff    = (unsigned int*)(ws + o_boff);
  unsigned int* hist    = (unsigned int*)(ws + o_hist);
  unsigned int* agg     = (unsigned int*)(ws + o_agg);
  unsigned int* cursor0 = (unsigned int*)(ws + o_curs0);
  float* coef           = (float*)(ws + o_coef);
  unsigned short* bFpack= (unsigned short*)(ws + o_frag);
  float* wpPack         = (float*)(ws + o_frag + 8192);
  float* biasF          = (float*)(ws + o_frag + 8192 + 12288);
  unsigned short* rank  = (unsigned short*)(ws + o_rank);
  int4* recS            = (int4*)(ws + o_rec);
  unsigned short* ybuf  = (unsigned short*)(ws + o_ybuf);
  unsigned short* sbuf  = (unsigned short*)(ws + o_sbuf);

  const double invE = 1.0 / (SCALE * (double)E);
  const double invN = 1.0 / (SCALE * (double)N);
  const int total = N * 64;
  const int nScanBlk = 49;  // ceil(50176/1024)

  hipMemsetAsync(d_ws, 0, zeroEnd, stream);

  hipLaunchKernelGGL(k_node, dim3(1024), dim3(256), 0, stream,
                     x, W1, b1, Ws, bs, ybuf, sbuf, stats, N, ei, hist, rank, E);
  hipLaunchKernelGGL(k_scan1, dim3(nScanBlk), dim3(256), 0, stream, hist, bsum);
  hipLaunchKernelGGL(k_scan2, dim3(1), dim3(64), 0, stream, bsum, boff, nScanBlk);
  hipLaunchKernelGGL(k_scan3, dim3(nScanBlk), dim3(256), 0, stream,
                     hist, boff, cursor0);
  hipLaunchKernelGGL(k_edge1, dim3(2048), dim3(256), 0, stream,
                     ei, pos, ybuf, W1, cursor0, rank, recS, stats, E);
  hipLaunchKernelGGL(k_coefA, dim3(1), dim3(64), 0, stream,
                     stats, g1, be1, W2, b2, W1, bFpack, wpPack, biasF, invE);
  {
    const int nchunk = E >> 7;
    const int blocks = (nchunk + 3) / 4;
    hipLaunchKernelGGL(k_edge2, dim3(blocks), dim3(256), 0, stream,
                       recS, ybuf, bFpack, wpPack, biasF, stats, agg, E);
  }
  hipLaunchKernelGGL(k_aggfix, dim3(1024), dim3(256), 0, stream, agg, stats, total);
  hipLaunchKernelGGL(k_coefB, dim3(1), dim3(64), 0, stream,
                     stats, g2, be2, gs, bes, gf, bef, coef, invE, invN, N);
  hipLaunchKernelGGL(k_final, dim3((total + 255) / 256), dim3(256), 0, stream,
                     agg, sbuf, coef, (float*)d_out, total);
}

// Round 10
// 273.929 us; speedup vs baseline: 1.3219x; 1.0267x over previous
//
#include <hip/hip_runtime.h>

#define CIN 61
constexpr float EPS = 1e-5f;
constexpr double SCALE = 16777216.0;  // 2^24 fixed-point deterministic stat sums

using s16x8 = __attribute__((ext_vector_type(8))) short;
using fx4   = __attribute__((ext_vector_type(4))) float;

static __device__ __forceinline__ unsigned short f2bf(float f) {
  unsigned int u = __float_as_uint(f);
  u = (u + 0x7fffu + ((u >> 16) & 1u)) >> 16;
  return (unsigned short)u;
}
static __device__ __forceinline__ float bf2f(unsigned short h) {
  return __uint_as_float(((unsigned int)h) << 16);
}

__device__ __forceinline__ void stat_reduce(float val, float* red, long long* dst_ll) {
  int tid = threadIdx.x;
  red[tid] = val;
  __syncthreads();
  if (tid < 64) {
    float t = red[tid] + red[tid + 64] + red[tid + 128] + red[tid + 192];
    atomicAdd((unsigned long long*)&dst_ll[tid],
              (unsigned long long)(long long)((double)t * SCALE));
  }
  __syncthreads();
}

// ---- fused node pass: y/s GEMVs (wave-private staging) + dst hist/rank ----
__global__ __launch_bounds__(256) void k_node(
    const float* __restrict__ x, const float* __restrict__ W1,
    const float* __restrict__ b1, const float* __restrict__ Ws,
    const float* __restrict__ bs, unsigned short* __restrict__ y,
    unsigned short* __restrict__ s_out, long long* __restrict__ stats, int N,
    const int* __restrict__ ei, unsigned int* __restrict__ hist,
    unsigned short* __restrict__ rank, int E) {
  const int tid = threadIdx.x, lane = tid & 63, wv = tid >> 6;
  float w1r[64], wsr[64];
#pragma unroll
  for (int k = 0; k < 64; ++k) {
    w1r[k] = (k < CIN) ? W1[k * 64 + lane] : 0.f;
    wsr[k] = (k < CIN) ? Ws[k * 64 + lane] : 0.f;
  }
  const float b1v = b1[lane], bsv = bs[lane];
  __shared__ float lrow[4][64];
  __shared__ float red[256];
  float ssum = 0.f, ssq = 0.f;
  const int nq = N >> 2;
  for (int q = blockIdx.x; q < nq; q += gridDim.x) {
    const int n = (q << 2) + wv;
    lrow[wv][lane] = (lane < CIN) ? x[(size_t)n * CIN + lane] : 0.f;
    __builtin_amdgcn_wave_barrier();
    float a0 = b1v, a1 = 0.f, a2 = 0.f, a3 = 0.f;
    float c0 = bsv, c1 = 0.f, c2 = 0.f, c3 = 0.f;
    const float4* rr = (const float4*)&lrow[wv][0];
#pragma unroll
    for (int k4 = 0; k4 < 16; ++k4) {
      float4 v = rr[k4];
      a0 = fmaf(v.x, w1r[4 * k4 + 0], a0);
      a1 = fmaf(v.y, w1r[4 * k4 + 1], a1);
      a2 = fmaf(v.z, w1r[4 * k4 + 2], a2);
      a3 = fmaf(v.w, w1r[4 * k4 + 3], a3);
      c0 = fmaf(v.x, wsr[4 * k4 + 0], c0);
      c1 = fmaf(v.y, wsr[4 * k4 + 1], c1);
      c2 = fmaf(v.z, wsr[4 * k4 + 2], c2);
      c3 = fmaf(v.w, wsr[4 * k4 + 3], c3);
    }
    y[(size_t)n * 64 + lane] = f2bf((a0 + a1) + (a2 + a3));
    const float sacc = (c0 + c1) + (c2 + c3);
    s_out[(size_t)n * 64 + lane] = f2bf(sacc);
    ssum += sacc;
    ssq = fmaf(sacc, sacc, ssq);
    __builtin_amdgcn_wave_barrier();
  }
  stat_reduce(ssum, red, stats + 256);
  stat_reduce(ssq, red, stats + 320);
  for (int i = blockIdx.x * 256 + tid; i < E; i += gridDim.x * 256) {
    const int dst = ei[E + i];
    rank[i] = (unsigned short)atomicAdd(&hist[dst], 1u);
  }
}

// ---- hierarchical scan ----
__global__ __launch_bounds__(256) void k_scan1(
    const unsigned int* __restrict__ hist, unsigned int* __restrict__ bsum) {
  const int tid = threadIdx.x, lane = tid & 63, wv = tid >> 6;
  const uint4 v = ((const uint4*)(hist + blockIdx.x * 1024))[tid];
  unsigned int s = v.x + v.y + v.z + v.w;
#pragma unroll
  for (int off = 1; off < 64; off <<= 1) s += __shfl_xor(s, off);
  __shared__ unsigned int wsum[4];
  if (lane == 0) wsum[wv] = s;
  __syncthreads();
  if (tid == 0) bsum[blockIdx.x] = wsum[0] + wsum[1] + wsum[2] + wsum[3];
}

__global__ void k_scan2(const unsigned int* __restrict__ bsum,
                        unsigned int* __restrict__ boff, int nb) {
  const int t = threadIdx.x;
  unsigned int v = (t < nb) ? bsum[t] : 0u;
  unsigned int incl = v;
#pragma unroll
  for (int off = 1; off < 64; off <<= 1) {
    unsigned int u = __shfl_up(incl, off);
    if (t >= off) incl += u;
  }
  if (t < nb) boff[t] = incl - v;
}

__global__ __launch_bounds__(256) void k_scan3(
    const unsigned int* __restrict__ hist, const unsigned int* __restrict__ boff,
    unsigned int* __restrict__ cursor0) {
  const int tid = threadIdx.x, lane = tid & 63, wv = tid >> 6;
  const uint4 v = ((const uint4*)(hist + blockIdx.x * 1024))[tid];
  const unsigned int s = v.x + v.y + v.z + v.w;
  unsigned int incl = s;
#pragma unroll
  for (int off = 1; off < 64; off <<= 1) {
    unsigned int u = __shfl_up(incl, off);
    if (lane >= off) incl += u;
  }
  __shared__ unsigned int wtot[4];
  if (lane == 63) wtot[wv] = incl;
  __syncthreads();
  unsigned int wb = boff[blockIdx.x];
#pragma unroll
  for (int k = 0; k < 4; ++k) wb += (k < wv) ? wtot[k] : 0u;
  const unsigned int ex = wb + incl - s;
  uint4 o;
  o.x = ex; o.y = ex + v.x; o.z = o.y + v.y; o.w = o.z + v.z;
  ((uint4*)(cursor0 + blockIdx.x * 1024))[tid] = o;
}

// ---- edge pass 1: 4 groups (32 edges) batched per wave iteration for MLP;
//      t1 stats + 16B sorted record {src,dst,pdiff} ----
__global__ __launch_bounds__(256) void k_edge1(
    const int* __restrict__ ei, const float* __restrict__ pos,
    const unsigned short* __restrict__ y, const float* __restrict__ W1,
    const unsigned int* __restrict__ cursor0, const unsigned short* __restrict__ rank,
    int4* __restrict__ recS, long long* __restrict__ stats, int E) {
  const int tid = threadIdx.x, lane = tid & 63, wv = tid >> 6;
  const int g8 = lane >> 3, c8 = lane & 7;
  float wp[3][8];
#pragma unroll
  for (int d = 0; d < 3; ++d)
#pragma unroll
    for (int i = 0; i < 8; ++i) wp[d][i] = W1[(61 + d) * 64 + 8 * c8 + i];
  float ssum[8] = {0.f, 0.f, 0.f, 0.f, 0.f, 0.f, 0.f, 0.f};
  float ssq[8]  = {0.f, 0.f, 0.f, 0.f, 0.f, 0.f, 0.f, 0.f};
  const int ngrp = E >> 3;
  const int nw = gridDim.x * 4;
  for (int q = blockIdx.x * 4 + wv; q < ngrp; q += 4 * nw) {
    const int qB = q + nw, qC = q + 2 * nw, qD = q + 3 * nw;
    const bool hB = qB < ngrp, hC = qC < ngrp, hD = qD < ngrp;
    const int eA = (q << 3) + g8;
    const int eB = hB ? (qB << 3) + g8 : eA;
    const int eC = hC ? (qC << 3) + g8 : eA;
    const int eD = hD ? (qD << 3) + g8 : eA;
    // all ei loads issued together (independent)
    const int srcA = ei[eA], dstA = ei[E + eA];
    const int srcB = ei[eB], dstB = ei[E + eB];
    const int srcC = ei[eC], dstC = ei[E + eC];
    const int srcD = ei[eD], dstD = ei[E + eD];
    // all gathers issued together
    float pvA = 0.f, pvB = 0.f, pvC = 0.f, pvD = 0.f;
    if (c8 < 3) {
      pvA = pos[srcA * 3 + c8] - pos[dstA * 3 + c8];
      pvB = pos[srcB * 3 + c8] - pos[dstB * 3 + c8];
      pvC = pos[srcC * 3 + c8] - pos[dstC * 3 + c8];
      pvD = pos[srcD * 3 + c8] - pos[dstD * 3 + c8];
    }
    const s16x8 yA = *(const s16x8*)(y + (unsigned)srcA * 64u + 8u * (unsigned)c8);
    const s16x8 yB = *(const s16x8*)(y + (unsigned)srcB * 64u + 8u * (unsigned)c8);
    const s16x8 yC = *(const s16x8*)(y + (unsigned)srcC * 64u + 8u * (unsigned)c8);
    const s16x8 yD = *(const s16x8*)(y + (unsigned)srcD * 64u + 8u * (unsigned)c8);
    unsigned offA = 0, offB = 0, offC = 0, offD = 0;
    if (c8 == 0) {
      offA = cursor0[dstA] + rank[eA];
      offB = cursor0[dstB] + rank[eB];
      offC = cursor0[dstC] + rank[eC];
      offD = cursor0[dstD] + rank[eD];
    }
#define EDGE1_BODY(SRC, DST, E_, PV, YV, OFF)                                   \
    {                                                                           \
      const float p0 = __shfl(PV, g8 * 8 + 0);                                  \
      const float p1 = __shfl(PV, g8 * 8 + 1);                                  \
      const float p2 = __shfl(PV, g8 * 8 + 2);                                  \
      _Pragma("unroll")                                                         \
      for (int i = 0; i < 8; ++i) {                                             \
        float v = bf2f((unsigned short)YV[i]);                                  \
        v = fmaf(p0, wp[0][i], v);                                              \
        v = fmaf(p1, wp[1][i], v);                                              \
        v = fmaf(p2, wp[2][i], v);                                              \
        v = fmaxf(v, 0.f);                                                      \
        ssum[i] += v;                                                           \
        ssq[i] = fmaf(v, v, ssq[i]);                                            \
      }                                                                         \
      if (c8 == 0) {                                                            \
        int4 r;                                                                 \
        r.x = (SRC & 0xffff) | (DST << 16);                                     \
        r.y = __float_as_int(p0);                                               \
        r.z = __float_as_int(p1);                                               \
        r.w = __float_as_int(p2);                                               \
        recS[OFF] = r;                                                          \
      }                                                                         \
    }
    EDGE1_BODY(srcA, dstA, eA, pvA, yA, offA)
    if (hB) EDGE1_BODY(srcB, dstB, eB, pvB, yB, offB)
    if (hC) EDGE1_BODY(srcC, dstC, eC, pvC, yC, offC)
    if (hD) EDGE1_BODY(srcD, dstD, eD, pvD, yD, offD)
#undef EDGE1_BODY
  }
#pragma unroll
  for (int i = 0; i < 8; ++i) {
    ssum[i] += __shfl_xor(ssum[i], 8);
    ssum[i] += __shfl_xor(ssum[i], 16);
    ssum[i] += __shfl_xor(ssum[i], 32);
    ssq[i] += __shfl_xor(ssq[i], 8);
    ssq[i] += __shfl_xor(ssq[i], 16);
    ssq[i] += __shfl_xor(ssq[i], 32);
  }
  __shared__ float sred[2][64];
  if (tid < 128) ((float*)sred)[tid] = 0.f;
  __syncthreads();
  if (g8 == 0) {
#pragma unroll
    for (int i = 0; i < 8; ++i) {
      atomicAdd(&sred[0][8 * c8 + i], ssum[i]);
      atomicAdd(&sred[1][8 * c8 + i], ssq[i]);
    }
  }
  __syncthreads();
  if (tid < 64) {
    atomicAdd((unsigned long long*)&stats[0 + tid],
              (unsigned long long)(long long)((double)sred[0][tid] * SCALE));
    atomicAdd((unsigned long long*)&stats[64 + tid],
              (unsigned long long)(long long)((double)sred[1][tid] * SCALE));
  }
}

// ---- BN1 coef + fold into W2, emitting pre-permuted per-lane fragment tables ----
__global__ void k_coefA(const long long* __restrict__ stats,
                        const float* __restrict__ g1, const float* __restrict__ be1,
                        const float* __restrict__ W2, const float* __restrict__ b2,
                        const float* __restrict__ W1,
                        unsigned short* __restrict__ bFpack,
                        float* __restrict__ wpPack, float* __restrict__ biasF,
                        double invE) {
  const int c = threadIdx.x;  // 64 threads; c plays "lane"
  __shared__ float a1s[64], c1s[64], b2sh[64];
  double m = (double)stats[c] * invE;
  double v = (double)stats[64 + c] * invE - m * m;
  float a = g1[c] * rsqrtf((float)v + EPS);
  a1s[c] = a;
  c1s[c] = fmaf(-(float)m, a, be1[c]);
  __syncthreads();
  float acc = b2[c];
  for (int k = 0; k < 64; ++k) acc = fmaf(c1s[k], W2[k * 64 + c], acc);
  b2sh[c] = acc;
  const int lg = c >> 4, l15 = c & 15;
#pragma unroll
  for (int t = 0; t < 4; ++t)
#pragma unroll
    for (int s = 0; s < 2; ++s)
#pragma unroll
      for (int i = 0; i < 8; ++i) {
        const int k = s * 32 + lg * 8 + i;
        bFpack[c * 64 + t * 16 + s * 8 + i] = f2bf(a1s[k] * W2[k * 64 + l15 + 16 * t]);
      }
#pragma unroll
  for (int d = 0; d < 3; ++d)
#pragma unroll
    for (int j = 0; j < 16; ++j) {
      const int k = (j < 8) ? (lg * 8 + j) : (32 + lg * 8 + (j - 8));
      wpPack[c * 48 + d * 16 + j] = W1[(61 + d) * 64 + k];
    }
  __syncthreads();
  float4 bf;
  bf.x = b2sh[l15]; bf.y = b2sh[l15 + 16]; bf.z = b2sh[l15 + 32]; bf.w = b2sh[l15 + 48];
  ((float4*)biasF)[c] = bf;
}

// ---- edge pass 2: 64-row chunks, pipelined rec/y, MFMA, register run-max ----
__global__ __launch_bounds__(256) void k_edge2(
    const int4* __restrict__ recS, const unsigned short* __restrict__ y,
    const unsigned short* __restrict__ bFpack, const float* __restrict__ wpPack,
    const float* __restrict__ biasF, long long* __restrict__ stats,
    unsigned int* __restrict__ agg, int E) {
  const int tid = threadIdx.x, lane = tid & 63, wv = tid >> 6;
  const int l15 = lane & 15, lg = lane >> 4;
  s16x8 bF[4][2];
  {
    const s16x8* bfp = (const s16x8*)(bFpack + (size_t)lane * 64);
#pragma unroll
    for (int t = 0; t < 4; ++t)
#pragma unroll
      for (int s = 0; s < 2; ++s) bF[t][s] = bfp[t * 2 + s];
  }
  float wpA[3][8], wpB[3][8];
  {
    const float4* wpp = (const float4*)(wpPack + (size_t)lane * 48);
#pragma unroll
    for (int d = 0; d < 3; ++d) {
      const float4 q0 = wpp[d * 4 + 0], q1 = wpp[d * 4 + 1];
      const float4 q2 = wpp[d * 4 + 2], q3 = wpp[d * 4 + 3];
      wpA[d][0] = q0.x; wpA[d][1] = q0.y; wpA[d][2] = q0.z; wpA[d][3] = q0.w;
      wpA[d][4] = q1.x; wpA[d][5] = q1.y; wpA[d][6] = q1.z; wpA[d][7] = q1.w;
      wpB[d][0] = q2.x; wpB[d][1] = q2.y; wpB[d][2] = q2.z; wpB[d][3] = q2.w;
      wpB[d][4] = q3.x; wpB[d][5] = q3.y; wpB[d][6] = q3.z; wpB[d][7] = q3.w;
    }
  }
  float bias[4];
  {
    const float4 bv = ((const float4*)biasF)[lane];
    bias[0] = bv.x; bias[1] = bv.y; bias[2] = bv.z; bias[3] = bv.w;
  }
  __shared__ float ld2[4][16][68];
  float ssum[4] = {0.f, 0.f, 0.f, 0.f}, ssq[4] = {0.f, 0.f, 0.f, 0.f};
  const int nchunk = E >> 6;  // 64 rows per chunk (E % 64 == 0)
  const int nw4 = gridDim.x * 4;
  for (int ch = blockIdx.x * 4 + wv; ch < nchunk; ch += nw4) {
    const int row0 = ch << 6;
    int4 rec = recS[row0 + l15];
    s16x8 yA, yB;
    {
      const unsigned srcP = (unsigned)rec.x & 0xffffu;
      const unsigned short* yr = y + srcP * 64u + (unsigned)(lg * 8);
      yA = *(const s16x8*)yr;
      yB = *(const s16x8*)(yr + 32);
    }
    int cur = -1;
    float m = 0.f;
    bool inside = false;
#pragma unroll
    for (int t4 = 0; t4 < 4; ++t4) {
      int4 recN;
      if (t4 < 3) recN = recS[row0 + ((t4 + 1) << 4) + l15];
      const int dstvCur = (int)(((unsigned)rec.x) >> 16);
      float p[3];
      p[0] = __int_as_float(rec.y);
      p[1] = __int_as_float(rec.z);
      p[2] = __int_as_float(rec.w);
      union { s16x8 v; unsigned int u[4]; } a0, a1;
#pragma unroll
      for (int h = 0; h < 4; ++h) {
        float f0 = bf2f((unsigned short)yA[2 * h]);
        float f1 = bf2f((unsigned short)yA[2 * h + 1]);
#pragma unroll
        for (int d = 0; d < 3; ++d) {
          f0 = fmaf(p[d], wpA[d][2 * h], f0);
          f1 = fmaf(p[d], wpA[d][2 * h + 1], f1);
        }
        f0 = fmaxf(f0, 0.f); f1 = fmaxf(f1, 0.f);
        asm("v_cvt_pk_bf16_f32 %0, %1, %2" : "=v"(a0.u[h]) : "v"(f0), "v"(f1));
        f0 = bf2f((unsigned short)yB[2 * h]);
        f1 = bf2f((unsigned short)yB[2 * h + 1]);
#pragma unroll
        for (int d = 0; d < 3; ++d) {
          f0 = fmaf(p[d], wpB[d][2 * h], f0);
          f1 = fmaf(p[d], wpB[d][2 * h + 1], f1);
        }
        f0 = fmaxf(f0, 0.f); f1 = fmaxf(f1, 0.f);
        asm("v_cvt_pk_bf16_f32 %0, %1, %2" : "=v"(a1.u[h]) : "v"(f0), "v"(f1));
      }
      fx4 acc[4];
#pragma unroll
      for (int t = 0; t < 4; ++t) {
        acc[t][0] = bias[t]; acc[t][1] = bias[t];
        acc[t][2] = bias[t]; acc[t][3] = bias[t];
      }
#pragma unroll
      for (int t = 0; t < 4; ++t) {
        acc[t] = __builtin_amdgcn_mfma_f32_16x16x32_bf16(a0.v, bF[t][0], acc[t], 0, 0, 0);
        acc[t] = __builtin_amdgcn_mfma_f32_16x16x32_bf16(a1.v, bF[t][1], acc[t], 0, 0, 0);
      }
#pragma unroll
      for (int t = 0; t < 4; ++t) {
        const int col = l15 + 16 * t;
#pragma unroll
        for (int j = 0; j < 4; ++j) {
          const float v = fmaxf(acc[t][j], 0.f);
          ssum[t] += v;
          ssq[t] = fmaf(v, v, ssq[t]);
          ld2[wv][lg * 4 + j][col] = v;
        }
      }
      __builtin_amdgcn_wave_barrier();  // LDS writes before reads
      // issue next tile's y gather; latency covered by run-max below
      s16x8 yAn, yBn;
      if (t4 < 3) {
        const unsigned srcN = (unsigned)recN.x & 0xffffu;
        const unsigned short* yrN = y + srcN * 64u + (unsigned)(lg * 8);
        yAn = *(const s16x8*)yrN;
        yBn = *(const s16x8*)(yrN + 32);
      }
      // prefetch all 16 transposed values (independent ds_reads, one latency)
      float v16[16];
#pragma unroll
      for (int r = 0; r < 16; ++r) v16[r] = ld2[wv][r][lane];
      // run-segmented max: dst via register shuffle (no LDS chain)
#pragma unroll
      for (int r = 0; r < 16; ++r) {
        const int d = __shfl(dstvCur, r);
        const float v = v16[r];
        if (d == cur) {
          m = fmaxf(m, v);
        } else {
          if (cur >= 0) {
            const unsigned int enc = __float_as_uint(m) | 0x80000000u;
            if (inside) agg[(unsigned)cur * 64u + lane] = enc;
            else atomicMax(&agg[(unsigned)cur * 64u + lane], enc);
          }
          cur = d;
          m = v;
          inside = (t4 > 0) || (r > 0);
        }
      }
      __builtin_amdgcn_wave_barrier();  // reads before next tile's writes
      if (t4 < 3) { rec = recN; yA = yAn; yB = yBn; }
    }
    if (cur >= 0)
      atomicMax(&agg[(unsigned)cur * 64u + lane], __float_as_uint(m) | 0x80000000u);
  }
#pragma unroll
  for (int t = 0; t < 4; ++t) {
    ssum[t] += __shfl_xor(ssum[t], 16); ssum[t] += __shfl_xor(ssum[t], 32);
    ssq[t]  += __shfl_xor(ssq[t], 16);  ssq[t]  += __shfl_xor(ssq[t], 32);
  }
  __shared__ float sred[2][64];
  if (tid < 128) ((float*)sred)[tid] = 0.f;
  __syncthreads();
  if (lg == 0) {
#pragma unroll
    for (int t = 0; t < 4; ++t) {
      atomicAdd(&sred[0][l15 + 16 * t], ssum[t]);
      atomicAdd(&sred[1][l15 + 16 * t], ssq[t]);
    }
  }
  __syncthreads();
  if (tid < 64) {
    atomicAdd((unsigned long long*)&stats[128 + tid],
              (unsigned long long)(long long)((double)sred[0][tid] * SCALE));
    atomicAdd((unsigned long long*)&stats[192 + tid],
              (unsigned long long)(long long)((double)sred[1][tid] * SCALE));
  }
}

// ---- stats of raw maxima over nonempty nodes + nonempty count ----
__global__ __launch_bounds__(256) void k_aggfix(
    const unsigned int* __restrict__ agg, long long* __restrict__ stats, int total) {
  const int tid = threadIdx.x;
  __shared__ float red[256];
  float ssum = 0.f, ssq = 0.f, kcf = 0.f;
  const int step = gridDim.x * 256;
  for (int i = blockIdx.x * 256 + tid; i < total; i += step) {
    const unsigned int u = agg[i];
    if (u >> 31) {
      const float v = __uint_as_float(u & 0x7fffffffu);
      ssum += v;
      ssq = fmaf(v, v, ssq);
      if ((i & 63) == 0) kcf += 1.f;
    }
  }
  stat_reduce(ssum, red, stats + 384);
  stat_reduce(ssq, red, stats + 448);
  stat_reduce(kcf, red, stats + 512);
}

// ---- remaining BN coefs composed for the final pass ----
__global__ void k_coefB(const long long* __restrict__ stats,
                        const float* __restrict__ g2, const float* __restrict__ be2,
                        const float* __restrict__ gs, const float* __restrict__ bes,
                        const float* __restrict__ gf, const float* __restrict__ bef,
                        float* __restrict__ coef, double invE, double invN, int N) {
  const int c = threadIdx.x;
  double m2 = (double)stats[128 + c] * invE;
  double v2 = (double)stats[192 + c] * invE - m2 * m2;
  float a2 = g2[c] * rsqrtf((float)v2 + EPS);
  float c2 = fmaf(-(float)m2, a2, be2[c]);
  double mS = (double)stats[256 + c] * invN;
  double vS = (double)stats[320 + c] * invN - mS * mS;
  float aS = gs[c] * rsqrtf((float)vS + EPS);
  float cS = fmaf(-(float)mS, aS, bes[c]);
  double su = (double)stats[384 + c] / SCALE;
  double qu = (double)stats[448 + c] / SCALE;
  double K  = (double)stats[512] / SCALE;
  double sv = (double)a2 * su + (double)c2 * K;
  double qv = (double)a2 * a2 * qu + 2.0 * a2 * c2 * su + (double)c2 * c2 * K;
  double mv = sv / N;
  double vv = qv / N - mv * mv;
  float aF = gf[c] * rsqrtf((float)vv + EPS);
  float cF = fmaf(-(float)mv, aF, bef[c]);
  coef[c]       = aF * a2;
  coef[64 + c]  = fmaf(aF, c2, cF);
  coef[128 + c] = cF;
  coef[192 + c] = aS;
  coef[256 + c] = cS;
}

__global__ __launch_bounds__(256) void k_final(
    const unsigned int* __restrict__ agg, const unsigned short* __restrict__ sbuf,
    const float* __restrict__ coef, float* __restrict__ out, int total) {
  int i = blockIdx.x * 256 + threadIdx.x;
  if (i >= total) return;
  const int c = i & 63;
  const unsigned int u = agg[i];
  float base;
  if (u >> 31)
    base = fmaf(coef[c], __uint_as_float(u & 0x7fffffffu), coef[64 + c]);
  else
    base = coef[128 + c];
  const float sv = fmaf(coef[192 + c], bf2f(sbuf[i]), coef[256 + c]);
  out[i] = fmaxf(base + sv, 0.f);
}

extern "C" void kernel_launch(void* const* d_in, const int* in_sizes, int n_in,
                              void* d_out, int out_size, void* d_ws, size_t ws_size,
                              hipStream_t stream) {
  const float* x   = (const float*)d_in[0];
  const float* pos = (const float*)d_in[1];
  const int*   ei  = (const int*)d_in[2];
  const float* W1  = (const float*)d_in[3];
  const float* b1  = (const float*)d_in[4];
  const float* g1  = (const float*)d_in[5];
  const float* be1 = (const float*)d_in[6];
  const float* W2  = (const float*)d_in[7];
  const float* b2  = (const float*)d_in[8];
  const float* g2  = (const float*)d_in[9];
  const float* be2 = (const float*)d_in[10];
  const float* Ws  = (const float*)d_in[11];
  const float* bs  = (const float*)d_in[12];
  const float* gs  = (const float*)d_in[13];
  const float* bes = (const float*)d_in[14];
  const float* gf  = (const float*)d_in[15];
  const float* bef = (const float*)d_in[16];
  const int N = in_sizes[0] / CIN;   // 50000
  const int E = in_sizes[2] / 2;     // 800000

  char* ws = (char*)d_ws;
  const size_t o_stats = 0;                            // 513 ll -> pad 4608
  const size_t o_bsum  = 4608;
  const size_t o_boff  = 5120;                         // page ends 8192
  const size_t o_hist  = 8192;                         // 50176 u32 (zeroed)
  const size_t o_agg   = o_hist + 200704;              // N*256
  const size_t zeroEnd = o_agg + (size_t)N * 256;
  const size_t o_curs0 = zeroEnd;                      // 200704
  const size_t o_coef  = o_curs0 + 200704;             // 4096
  const size_t o_frag  = o_coef + 4096;                // bFpack 8192 | wpPack 12288 | biasF 1024
  const size_t o_rank  = o_frag + 24576;               // E*2
  const size_t o_rec   = o_rank + (size_t)E * 2;       // E*16
  const size_t o_ybuf  = o_rec + (size_t)E * 16;       // N*128
  const size_t o_sbuf  = o_ybuf + (size_t)N * 128;     // N*128

  long long* stats      = (long long*)(ws + o_stats);
  unsigned int* bsum    = (unsigned int*)(ws + o_bsum);
  unsigned int* boff    = (unsigned int*)(ws + o_boff);
  unsigned int* hist    = (unsigned int*)(ws + o_hist);
  unsigned int* agg     = (unsigned int*)(ws + o_agg);
  unsigned int* cursor0 = (unsigned int*)(ws + o_curs0);
  float* coef           = (float*)(ws + o_coef);
  unsigned short* bFpack= (unsigned short*)(ws + o_frag);
  float* wpPack         = (float*)(ws + o_frag + 8192);
  float* biasF          = (float*)(ws + o_frag + 8192 + 12288);
  unsigned short* rank  = (unsigned short*)(ws + o_rank);
  int4* recS            = (int4*)(ws + o_rec);
  unsigned short* ybuf  = (unsigned short*)(ws + o_ybuf);
  unsigned short* sbuf  = (unsigned short*)(ws + o_sbuf);

  const double invE = 1.0 / (SCALE * (double)E);
  const double invN = 1.0 / (SCALE * (double)N);
  const int total = N * 64;
  const int nScanBlk = 49;  // ceil(50176/1024)

  hipMemsetAsync(d_ws, 0, zeroEnd, stream);

  hipLaunchKernelGGL(k_node, dim3(1024), dim3(256), 0, stream,
                     x, W1, b1, Ws, bs, ybuf, sbuf, stats, N, ei, hist, rank, E);
  hipLaunchKernelGGL(k_scan1, dim3(nScanBlk), dim3(256), 0, stream, hist, bsum);
  hipLaunchKernelGGL(k_scan2, dim3(1), dim3(64), 0, stream, bsum, boff, nScanBlk);
  hipLaunchKernelGGL(k_scan3, dim3(nScanBlk), dim3(256), 0, stream,
                     hist, boff, cursor0);
  hipLaunchKernelGGL(k_edge1, dim3(2048), dim3(256), 0, stream,
                     ei, pos, ybuf, W1, cursor0, rank, recS, stats, E);
  hipLaunchKernelGGL(k_coefA, dim3(1), dim3(64), 0, stream,
                     stats, g1, be1, W2, b2, W1, bFpack, wpPack, biasF, invE);
  hipLaunchKernelGGL(k_edge2, dim3(1563), dim3(256), 0, stream,
                     recS, ybuf, bFpack, wpPack, biasF, stats, agg, E);
  hipLaunchKernelGGL(k_aggfix, dim3(1024), dim3(256), 0, stream, agg, stats, total);
  hipLaunchKernelGGL(k_coefB, dim3(1), dim3(64), 0, stream,
                     stats, g2, be2, gs, bes, gf, bef, coef, invE, invN, N);
  hipLaunchKernelGGL(k_final, dim3((total + 255) / 256), dim3(256), 0, stream,
                     agg, sbuf, coef, (float*)d_out, total);
}